// Round 9
// baseline (166.566 us; speedup 1.0000x reference)
//
#include <hip/hip_runtime.h>
#include <cmath>

#define CDIM 384
#define NB 8
#define NPIX 1024

typedef __attribute__((ext_vector_type(8))) short short8v;
typedef __attribute__((ext_vector_type(4))) float float4v;

__device__ __forceinline__ ushort f2bf(float f) {
  union { float f; unsigned u; } v; v.f = f;
  unsigned r = (v.u + 0x7fffu + ((v.u >> 16) & 1u)) >> 16;
  return (ushort)r;
}
__device__ __forceinline__ float bf2f(ushort u) {
  union { unsigned u; float f; } v; v.u = ((unsigned)u) << 16;
  return v.f;
}

// ---------------------------------------------------------------------------
// Kernel 0: bf16 twiddle tables into ws.
// ---------------------------------------------------------------------------
__global__ __launch_bounds__(256) void tables_k(ushort* __restrict__ tbl) {
  int i = blockIdx.x * 256 + threadIdx.x;
  if (i >= 5 * 1024) return;
  int t = i >> 10, j = i & 1023, r = j >> 5, cidx = j & 31;
  float ang = (float)((r * cidx) & 31) * 0.19634954084936207f;
  float val;
  if (t == 0) val = cosf(ang);
  else if (t == 1) val = sinf(ang);
  else if (t == 2) val = -sinf(ang);
  else {
    if (cidx > 16) val = 0.f;
    else {
      float cv = (cidx == 0 || cidx == 16) ? 1.f : 2.f;
      val = (t == 3) ? cv * cosf(ang) : -cv * sinf(ang);
    }
  }
  tbl[i] = f2bf(val);
}

// ---------------------------------------------------------------------------
// Kernel 0b: x (b,n,c) f32 -> xc (b,c,n) bf16.  LDS tile, both sides coalesced.
// ---------------------------------------------------------------------------
__global__ __launch_bounds__(256) void xtrans_k(
    const float* __restrict__ x, ushort* __restrict__ xc)
{
  const int b = blockIdx.x, c0 = blockIdx.y * 32, n0 = blockIdx.z * 128;
  __shared__ ushort T[128][33];
  for (int i = threadIdx.x; i < 4096; i += 256) {
    int n = i >> 5, c = i & 31;
    T[n][c] = f2bf(x[((long)(b * 1024 + n0 + n)) * CDIM + c0 + c]);
  }
  __syncthreads();
  for (int i = threadIdx.x; i < 4096; i += 256) {
    int c = i >> 7, n = i & 127;
    xc[((long)(b * CDIM + c0 + c)) * 1024 + n0 + n] = T[n][c];
  }
}

// ---------------------------------------------------------------------------
// Kernel 1: spectral filter via MFMA + FUSED depthwise conv3x3 + BN.
// ---------------------------------------------------------------------------
__global__ __launch_bounds__(256) void fft_conv_k(
    const ushort* __restrict__ xc, const float* __restrict__ cw,
    const ushort* __restrict__ tbl,
    const float* __restrict__ dwq, const float* __restrict__ dwk, const float* __restrict__ dwv,
    const float* __restrict__ gq, const float* __restrict__ bq, const float* __restrict__ mq, const float* __restrict__ vq,
    const float* __restrict__ gk, const float* __restrict__ bk, const float* __restrict__ mk, const float* __restrict__ vk,
    const float* __restrict__ gv, const float* __restrict__ bv, const float* __restrict__ mv, const float* __restrict__ vv,
    ushort* __restrict__ yc,
    ushort* __restrict__ qc, ushort* __restrict__ kc, ushort* __restrict__ vc)
{
  const int b = blockIdx.x / CDIM, c = blockIdx.x % CDIM;
  const int tid = threadIdx.x;
  const int w = tid >> 6, lane = tid & 63;
  const int l15 = lane & 15, l16 = lane >> 4;
  __shared__ ushort B[11][32][40];
  __shared__ float Ysf[32][33];

  float wq9[9], wk9[9], wv9[9];
#pragma unroll
  for (int t = 0; t < 9; ++t) {
    wq9[t] = dwq[c * 9 + t];
    wk9[t] = dwk[c * 9 + t];
    wv9[t] = dwv[c * 9 + t];
  }
  float scq = gq[c] * rsqrtf(vq[c] + 1e-5f); float shq = bq[c] - mq[c] * scq;
  float sck = gk[c] * rsqrtf(vk[c] + 1e-5f); float shk = bk[c] - mk[c] * sck;
  float scv = gv[c] * rsqrtf(vv[c] + 1e-5f); float shv = bv[c] - mv[c] * scv;

  for (int i = tid; i < 640; i += 256) {                 // tables -> LDS
    int t = i >> 7, j = i & 127, r = j >> 2, s = j & 3;
    *(uint4*)&B[t][r][s * 8] = *(const uint4*)&tbl[t * 1024 + r * 32 + s * 8];
  }
  for (int i = tid; i < 1024; i += 256)                  // input -> Xt[w][h]
    B[5][i & 31][i >> 5] = xc[(long)(b * CDIM + c) * 1024 + i];
  __syncthreads();

  // stage1: R1[u,w] = sum_h Tc[u,h]*Xt[w,h];  I1 = sum_h Tsn[u,h]*Xt[w,h]
  for (int j = w; j < 8; j += 4) {
    int o = j & 1, ut = (j >> 1) & 1, wt = (j >> 2) & 1;
    short8v af = *(const short8v*)&B[o == 0 ? 0 : 2][ut * 16 + l15][l16 * 8];
    short8v bf = *(const short8v*)&B[5][wt * 16 + l15][l16 * 8];
    float4v acc = {0.f, 0.f, 0.f, 0.f};
    acc = __builtin_amdgcn_mfma_f32_16x16x32_bf16(af, bf, acc, 0, 0, 0);
    int dst = (o == 0) ? 7 : 8;
#pragma unroll
    for (int r = 0; r < 4; ++r)
      B[dst][ut * 16 + l16 * 4 + r][wt * 16 + l15] = f2bf(acc[r]);
  }
  __syncthreads();

  // stage2: Xfr[u,v] = R1.Tc + I1.Ts ; Xfi = I1.Tc + R1.Tsn  (fp32 raw store)
  for (int j = w; j < 8; j += 4) {
    int o = j & 1, ut = (j >> 1) & 1, vt = (j >> 2) & 1;
    short8v a1 = *(const short8v*)&B[o == 0 ? 7 : 8][ut * 16 + l15][l16 * 8];
    short8v b1 = *(const short8v*)&B[0][vt * 16 + l15][l16 * 8];
    short8v a2 = *(const short8v*)&B[o == 0 ? 8 : 7][ut * 16 + l15][l16 * 8];
    short8v b2 = *(const short8v*)&B[o == 0 ? 1 : 2][vt * 16 + l15][l16 * 8];
    float4v acc = {0.f, 0.f, 0.f, 0.f};
    acc = __builtin_amdgcn_mfma_f32_16x16x32_bf16(a1, b1, acc, 0, 0, 0);
    acc = __builtin_amdgcn_mfma_f32_16x16x32_bf16(a2, b2, acc, 0, 0, 0);
    int v = vt * 16 + l15;
    if (v < 17) {
      float* praw = (float*)&B[o == 0 ? 5 : 6][0][0];    // [32][20] f32 view
#pragma unroll
      for (int r = 0; r < 4; ++r)
        praw[(ut * 16 + l16 * 4 + r) * 20 + v] = acc[r];
    }
  }
  __syncthreads();

  // zero Ytr/Yti rows 17..31, then weight-multiply + transpose scatter
  for (int i = tid; i < 150; i += 256) {
    int buf = i / 75, j2 = i % 75, r2 = 17 + j2 / 5, s2 = j2 % 5;
    uint4 z = {0u, 0u, 0u, 0u};
    *(uint4*)&B[9 + buf][r2][s2 * 8] = z;
  }
  {
    const float* xfr = (const float*)&B[5][0][0];
    const float* xfi = (const float*)&B[6][0][0];
    for (int e = tid; e < 544; e += 256) {
      int u = e / 17, v = e - u * 17;
      float fr = xfr[u * 20 + v], fi = xfi[u * 20 + v];
      float2 wc = *(const float2*)&cw[((long)(c * 32 + u) * 17 + v) * 2];
      B[9][v][u]  = f2bf(fr * wc.x - fi * wc.y);
      B[10][v][u] = f2bf(fr * wc.y + fi * wc.x);
    }
  }
  __syncthreads();

  // stage3: Zr[h,v] = Tc(h).Ytr + Tsn(h).Yti ; Zi = Tc(h).Yti + Ts(h).Ytr
  for (int j = w; j < 8; j += 4) {
    int o = j & 1, ht = (j >> 1) & 1, vt = (j >> 2) & 1;
    short8v a1 = *(const short8v*)&B[0][ht * 16 + l15][l16 * 8];
    short8v b1 = *(const short8v*)&B[o == 0 ? 9 : 10][vt * 16 + l15][l16 * 8];
    short8v a2 = *(const short8v*)&B[o == 0 ? 2 : 1][ht * 16 + l15][l16 * 8];
    short8v b2 = *(const short8v*)&B[o == 0 ? 10 : 9][vt * 16 + l15][l16 * 8];
    float4v acc = {0.f, 0.f, 0.f, 0.f};
    acc = __builtin_amdgcn_mfma_f32_16x16x32_bf16(a1, b1, acc, 0, 0, 0);
    acc = __builtin_amdgcn_mfma_f32_16x16x32_bf16(a2, b2, acc, 0, 0, 0);
    int dst = (o == 0) ? 7 : 8;
#pragma unroll
    for (int r = 0; r < 4; ++r)
      B[dst][ht * 16 + l16 * 4 + r][vt * 16 + l15] = f2bf(acc[r]);
  }
  __syncthreads();

  // stage4: y[h,w] = (Zr.Uc^T + Zi.Us^T)/1024 -> Ysf (LDS) + yc (coalesced)
  {
    int ht = w & 1, wt = (w >> 1) & 1;
    short8v a1 = *(const short8v*)&B[7][ht * 16 + l15][l16 * 8];
    short8v b1 = *(const short8v*)&B[3][wt * 16 + l15][l16 * 8];
    short8v a2 = *(const short8v*)&B[8][ht * 16 + l15][l16 * 8];
    short8v b2 = *(const short8v*)&B[4][wt * 16 + l15][l16 * 8];
    float4v acc = {0.f, 0.f, 0.f, 0.f};
    acc = __builtin_amdgcn_mfma_f32_16x16x32_bf16(a1, b1, acc, 0, 0, 0);
    acc = __builtin_amdgcn_mfma_f32_16x16x32_bf16(a2, b2, acc, 0, 0, 0);
#pragma unroll
    for (int r = 0; r < 4; ++r) {
      int hh = ht * 16 + l16 * 4 + r, ww = wt * 16 + l15;
      float y = acc[r] * (1.0f / 1024.0f);
      Ysf[hh][ww] = y;
      yc[(long)(b * CDIM + c) * 1024 + hh * 32 + ww] = f2bf(y);
    }
  }
  __syncthreads();

  // fused depthwise 3x3 conv + BN -> qc/kc/vc (bf16, b,c,n — coalesced)
  for (int i = tid; i < 1024; i += 256) {
    int hh = i >> 5, ww = i & 31;
    float aq = 0.f, ak = 0.f, av = 0.f;
#pragma unroll
    for (int dy = 0; dy < 3; ++dy) {
      int y0 = hh + dy - 1;
#pragma unroll
      for (int dx = 0; dx < 3; ++dx) {
        int x0 = ww + dx - 1;
        float xv = (y0 >= 0 && y0 < 32 && x0 >= 0 && x0 < 32) ? Ysf[y0][x0] : 0.f;
        int t = dy * 3 + dx;
        aq += xv * wq9[t]; ak += xv * wk9[t]; av += xv * wv9[t];
      }
    }
    long o = (long)(b * CDIM + c) * 1024 + i;
    qc[o] = f2bf(aq * scq + shq);
    kc[o] = f2bf(ak * sck + shk);
    vc[o] = f2bf(av * scv + shv);
  }
}

// ---------------------------------------------------------------------------
// Kernel 1b: transpose (b,c,n)->(b,n,c): yc->out (f32), qc/kc/vc->q0/k0/v0.
// ---------------------------------------------------------------------------
__global__ __launch_bounds__(256) void trans_k(
    const ushort* __restrict__ yc, const ushort* __restrict__ qc,
    const ushort* __restrict__ kc, const ushort* __restrict__ vc,
    float* __restrict__ out, ushort* __restrict__ q0,
    ushort* __restrict__ k0, ushort* __restrict__ v0)
{
  const int b = blockIdx.x, c0 = blockIdx.y * 32, n0 = blockIdx.z * 128;
  __shared__ ushort T[128][33];
  const ushort* srcs[4] = {yc, qc, kc, vc};
#pragma unroll
  for (int p = 0; p < 4; ++p) {
    if (p) __syncthreads();
    const ushort* s = srcs[p];
    for (int i = threadIdx.x; i < 4096; i += 256) {
      int c = i >> 7, n = i & 127;
      T[n][c] = s[((long)(b * CDIM + c0 + c)) * 1024 + n0 + n];
    }
    __syncthreads();
    for (int i = threadIdx.x; i < 4096; i += 256) {
      int n = i >> 5, c = i & 31;
      long o = ((long)(b * 1024 + n0 + n)) * CDIM + c0 + c;
      ushort v = T[n][c];
      if (p == 0)      out[o] = bf2f(v);
      else if (p == 1) q0[o] = v;
      else if (p == 2) k0[o] = v;
      else             v0[o] = v;
    }
  }
}

// ---------------------------------------------------------------------------
// Kernel 2b: convert the 4 projection weights to bf16
// ---------------------------------------------------------------------------
__global__ __launch_bounds__(256) void wconv_k(
    const float* __restrict__ a, const float* __restrict__ b,
    const float* __restrict__ c, const float* __restrict__ d,
    ushort* __restrict__ oa, ushort* __restrict__ ob,
    ushort* __restrict__ oc, ushort* __restrict__ od)
{
  int i = blockIdx.x * 256 + threadIdx.x;
  if (i * 4 >= CDIM * CDIM) return;
  float4 va = *(const float4*)&a[i * 4];
  float4 vb = *(const float4*)&b[i * 4];
  float4 vc = *(const float4*)&c[i * 4];
  float4 vd = *(const float4*)&d[i * 4];
  ushort4 ra = { f2bf(va.x), f2bf(va.y), f2bf(va.z), f2bf(va.w) };
  ushort4 rb = { f2bf(vb.x), f2bf(vb.y), f2bf(vb.z), f2bf(vb.w) };
  ushort4 rc = { f2bf(vc.x), f2bf(vc.y), f2bf(vc.z), f2bf(vc.w) };
  ushort4 rd = { f2bf(vd.x), f2bf(vd.y), f2bf(vd.z), f2bf(vd.w) };
  *(ushort4*)&oa[i * 4] = ra;
  *(ushort4*)&ob[i * 4] = rb;
  *(ushort4*)&oc[i * 4] = rc;
  *(ushort4*)&od[i * 4] = rd;
}

// ---------------------------------------------------------------------------
// MFMA GEMM body  C[m,n'] = sum_k A[m,k] W[n',k]
// tile 128x128, BK=64, 4 waves (2x2, 64x64 each), padded LDS stride 72.
// flags==0: bf16 store.  flags==1: fp32 RMW  out += acc + bias.
// ---------------------------------------------------------------------------
__device__ __forceinline__ void gemm_body(
    const ushort* __restrict__ A, const ushort* __restrict__ Wb,
    const float* __restrict__ bias, void* __restrict__ Cd, int flags,
    int bx, int by)
{
  __shared__ ushort As[128][72];
  __shared__ ushort Bs[128][72];
  const int tid = threadIdx.x;
  const int w = tid >> 6, lane = tid & 63;
  const int l15 = lane & 15, l16 = lane >> 4;
  const int wm = w >> 1, wn = w & 1;
  const int row0 = bx * 128, col0 = by * 128;
  float4v acc[4][4];
#pragma unroll
  for (int i = 0; i < 4; ++i)
#pragma unroll
    for (int j = 0; j < 4; ++j) acc[i][j] = (float4v){0.f, 0.f, 0.f, 0.f};
  for (int kt = 0; kt < CDIM; kt += 64) {
    if (kt) __syncthreads();
    for (int c = tid; c < 1024; c += 256) {
      int r = c >> 3, s = c & 7;
      *(uint4*)&As[r][s * 8] = *(const uint4*)&A[(long)(row0 + r) * CDIM + kt + s * 8];
    }
    for (int c = tid; c < 1024; c += 256) {
      int r = c >> 3, s = c & 7;
      *(uint4*)&Bs[r][s * 8] = *(const uint4*)&Wb[(long)(col0 + r) * CDIM + kt + s * 8];
    }
    __syncthreads();
#pragma unroll
    for (int s = 0; s < 2; ++s) {
      short8v a[4], bfr[4];
#pragma unroll
      for (int i = 0; i < 4; ++i)
        a[i] = *(const short8v*)&As[wm * 64 + i * 16 + l15][s * 32 + l16 * 8];
#pragma unroll
      for (int j = 0; j < 4; ++j)
        bfr[j] = *(const short8v*)&Bs[wn * 64 + j * 16 + l15][s * 32 + l16 * 8];
#pragma unroll
      for (int i = 0; i < 4; ++i)
#pragma unroll
        for (int j = 0; j < 4; ++j)
          acc[i][j] = __builtin_amdgcn_mfma_f32_16x16x32_bf16(a[i], bfr[j], acc[i][j], 0, 0, 0);
    }
  }
#pragma unroll
  for (int i = 0; i < 4; ++i)
#pragma unroll
    for (int j = 0; j < 4; ++j) {
      int col = col0 + wn * 64 + j * 16 + l15;
      int rbase = row0 + wm * 64 + i * 16 + l16 * 4;
#pragma unroll
      for (int r = 0; r < 4; ++r) {
        long o = (long)(rbase + r) * CDIM + col;
        if (flags == 0) ((ushort*)Cd)[o] = f2bf(acc[i][j][r]);
        else            ((float*)Cd)[o] += acc[i][j][r] + bias[col];
      }
    }
}

// fused q/k/v projection GEMMs (blockIdx.z selects)
__global__ __launch_bounds__(256) void gemm_qkv_k(
    const ushort* __restrict__ q0, const ushort* __restrict__ k0, const ushort* __restrict__ v0,
    const ushort* __restrict__ wqb, const ushort* __restrict__ wkb, const ushort* __restrict__ wvb,
    ushort* __restrict__ q1, ushort* __restrict__ k1, ushort* __restrict__ v1)
{
  const int z = blockIdx.z;
  const ushort* A  = z == 0 ? q0  : z == 1 ? k0  : v0;
  const ushort* Wb = z == 0 ? wqb : z == 1 ? wkb : wvb;
  ushort*       C  = z == 0 ? q1  : z == 1 ? k1  : v1;
  gemm_body(A, Wb, nullptr, C, 0, blockIdx.x, blockIdx.y);
}

// final projection: out += A@wo^T + bo
__global__ __launch_bounds__(256) void gemm_out_k(
    const ushort* __restrict__ A, const ushort* __restrict__ Wb,
    const float* __restrict__ bias, float* __restrict__ Cd)
{
  gemm_body(A, Wb, bias, Cd, 1, blockIdx.x, blockIdx.y);
}

// ---------------------------------------------------------------------------
// Kernel 3b: V transpose  v1 (b,n,h*48+d) -> vt ((b*8+h)*48+d, n)
// ---------------------------------------------------------------------------
__global__ __launch_bounds__(256) void vtrans_k(
    const ushort* __restrict__ v1, ushort* __restrict__ vt)
{
  const int bh = blockIdx.x, b = bh >> 3, h = bh & 7;
  const int n0 = blockIdx.y * 64;
  const int tid = threadIdx.x;
  __shared__ unsigned Lu[64][49];
  for (int i = tid; i < 384; i += 256) {
    int r = i / 6, s = i - r * 6;
    uint4 p = *(const uint4*)&v1[(long)(b * 1024 + n0 + r) * CDIM + h * 48 + s * 8];
    unsigned d0 = s * 8;
    Lu[r][d0 + 0] = p.x & 0xffffu;        Lu[r][d0 + 1] = p.x >> 16;
    Lu[r][d0 + 2] = p.y & 0xffffu;        Lu[r][d0 + 3] = p.y >> 16;
    Lu[r][d0 + 4] = p.z & 0xffffu;        Lu[r][d0 + 5] = p.z >> 16;
    Lu[r][d0 + 6] = p.w & 0xffffu;        Lu[r][d0 + 7] = p.w >> 16;
  }
  __syncthreads();
  for (int i = tid; i < 384; i += 256) {
    int d = i >> 3, s = i & 7;
    uint4 o;
    o.x = Lu[s * 8 + 0][d] | (Lu[s * 8 + 1][d] << 16);
    o.y = Lu[s * 8 + 2][d] | (Lu[s * 8 + 3][d] << 16);
    o.z = Lu[s * 8 + 4][d] | (Lu[s * 8 + 5][d] << 16);
    o.w = Lu[s * 8 + 6][d] | (Lu[s * 8 + 7][d] << 16);
    *(uint4*)&vt[((long)bh * 48 + d) * NPIX + n0 + s * 8] = o;
  }
}

// ---------------------------------------------------------------------------
// Kernel 4: MFMA flash attention.
//  - no-max softmax + ones-MFMA row sums (round 7)
//  - Ps XOR-swizzle: write col ^((l16&2)<<3), read col ^((l15>>3)<<4)
//    -> Ps scalar-store banks disjoint per l16 group (was 4-way conflict)
//  - T14 pipeline: 2 KV LDS buffers, loads for tile t+1 issued (scalars, no
//    arrays) before compute(t), ds_writes after compute, ONE barrier/iter.
// ---------------------------------------------------------------------------
__global__ __launch_bounds__(256) void attn_mfma_k(
    const ushort* __restrict__ q1, const ushort* __restrict__ k1,
    const ushort* __restrict__ vt, ushort* __restrict__ ao)
{
  const int bh = blockIdx.x, qt = blockIdx.y;
  const int b = bh >> 3, h = bh & 7;
  const int tid = threadIdx.x;
  const int w = tid >> 6, lane = tid & 63;
  const int l15 = lane & 15, l16 = lane >> 4;
  __shared__ ushort Qs[64][72], Ps[64][72];
  __shared__ ushort KV0[112][72], KV1[112][72];  // rows 0..63 K (pad 48..63=0), 64..111 V^T
  const float scale = 0.051031036307982884f;  // 384^-0.5
  const long base = (long)b * NPIX * CDIM + h * 48;
  const long vbase = (long)bh * 48 * NPIX;
  const int pswz = (l16 & 2) << 3;            // Ps write-col swizzle
  const int pxor = (l15 >> 3) << 4;           // Ps read-col swizzle

  // per-thread staging descriptors (scalars, no arrays -> no scratch)
  // chunk0: i=tid (<384, always K); chunk1: tid+256 (mixed); chunk2: tid+512 (always V)
  const int i0 = tid, i1 = tid + 256, i2 = tid + 512;
  const int r0 = i0 / 6, s0 = i0 - r0 * 6;
  const ushort* gp0 = k1 + base + (long)r0 * CDIM + s0 * 8;
  const long st0 = (long)64 * CDIM;
  const int lo0 = r0 * 72 + s0 * 8;
  const ushort* gp1; long st1; int lo1;
  if (i1 < 384) {
    int r = i1 / 6, s = i1 - r * 6;
    gp1 = k1 + base + (long)r * CDIM + s * 8; st1 = (long)64 * CDIM; lo1 = r * 72 + s * 8;
  } else {
    int j = i1 - 384, d = j >> 3, s = j & 7;
    gp1 = vt + vbase + (long)d * NPIX + s * 8; st1 = 64; lo1 = (64 + d) * 72 + s * 8;
  }
  const int j2 = i2 - 384, d2 = j2 >> 3, s2 = j2 & 7;
  const ushort* gp2 = vt + vbase + (long)d2 * NPIX + s2 * 8;
  const long st2 = 64;
  const int lo2 = (64 + d2) * 72 + s2 * 8;

#define LOADT(KT) do { \
    t0 = *(const uint4*)(gp0 + (long)(KT) * st0); \
    t1 = *(const uint4*)(gp1 + (long)(KT) * st1); \
    t2 = *(const uint4*)(gp2 + (long)(KT) * st2); } while (0)
#define WRT(KVB) do { \
    *(uint4*)((ushort*)&KVB[0][0] + lo0) = t0; \
    *(uint4*)((ushort*)&KVB[0][0] + lo1) = t1; \
    *(uint4*)((ushort*)&KVB[0][0] + lo2) = t2; } while (0)
#define COMPUTE(KVB) do { \
    float4v sacc[4]; \
    _Pragma("unroll") \
    for (int fc = 0; fc < 4; ++fc) { \
      short8v kb0 = *(const short8v*)&KVB[fc * 16 + l15][l16 * 8]; \
      short8v kb1 = *(const short8v*)&KVB[fc * 16 + l15][32 + l16 * 8]; \
      sacc[fc] = (float4v){0.f, 0.f, 0.f, 0.f}; \
      sacc[fc] = __builtin_amdgcn_mfma_f32_16x16x32_bf16(qa0, kb0, sacc[fc], 0, 0, 0); \
      sacc[fc] = __builtin_amdgcn_mfma_f32_16x16x32_bf16(qa1, kb1, sacc[fc], 0, 0, 0); \
    } \
    _Pragma("unroll") \
    for (int fc = 0; fc < 4; ++fc) \
      _Pragma("unroll") \
      for (int r = 0; r < 4; ++r) \
        Ps[w * 16 + l16 * 4 + r][(fc * 16 + l15) ^ pswz] = f2bf(__expf(sacc[fc][r] * scale)); \
    asm volatile("s_waitcnt lgkmcnt(0)" ::: "memory"); \
    __builtin_amdgcn_sched_barrier(0); \
    short8v pa0 = *(const short8v*)&Ps[w * 16 + l15][(l16 * 8) ^ pxor]; \
    short8v pa1 = *(const short8v*)&Ps[w * 16 + l15][(32 + l16 * 8) ^ pxor]; \
    float4v srow = (float4v){0.f, 0.f, 0.f, 0.f}; \
    srow = __builtin_amdgcn_mfma_f32_16x16x32_bf16(pa0, onesb, srow, 0, 0, 0); \
    srow = __builtin_amdgcn_mfma_f32_16x16x32_bf16(pa1, onesb, srow, 0, 0, 0); \
    _Pragma("unroll") \
    for (int r = 0; r < 4; ++r) lrun[r] += srow[r]; \
    _Pragma("unroll") \
    for (int fd = 0; fd < 3; ++fd) { \
      short8v vb0 = *(const short8v*)&KVB[64 + fd * 16 + l15][l16 * 8]; \
      short8v vb1 = *(const short8v*)&KVB[64 + fd * 16 + l15][32 + l16 * 8]; \
      accO[fd] = __builtin_amdgcn_mfma_f32_16x16x32_bf16(pa0, vb0, accO[fd], 0, 0, 0); \
      accO[fd] = __builtin_amdgcn_mfma_f32_16x16x32_bf16(pa1, vb1, accO[fd], 0, 0, 0); \
    } } while (0)

  // prologue: zero K-pads (Qs, KV0, KV1), stage Q, stage tile 0
  {
    uint4 z4 = {0u, 0u, 0u, 0u};
    for (int i = tid; i < 384; i += 256) {
      int a = i >> 7, r = (i >> 1) & 63, s = i & 1;
      if (a == 0)      *(uint4*)&Qs[r][48 + s * 8] = z4;
      else if (a == 1) *(uint4*)&KV0[r][48 + s * 8] = z4;
      else             *(uint4*)&KV1[r][48 + s * 8] = z4;
    }
  }
  for (int i = tid; i < 384; i += 256) {
    int r = i / 6, s = i - r * 6;
    *(uint4*)&Qs[r][s * 8] = *(const uint4*)&q1[base + (long)(qt * 64 + r) * CDIM + s * 8];
  }
  uint4 t0, t1, t2;
  LOADT(0);
  WRT(KV0);
  __syncthreads();

  float lrun[4] = {0.f, 0.f, 0.f, 0.f};
  float4v accO[3];
#pragma unroll
  for (int fd = 0; fd < 3; ++fd) accO[fd] = (float4v){0.f, 0.f, 0.f, 0.f};
  short8v onesb;
#pragma unroll
  for (int j = 0; j < 8; ++j) onesb[j] = (short)0x3F80;  // bf16 1.0
  const short8v qa0 = *(const short8v*)&Qs[w * 16 + l15][l16 * 8];
  const short8v qa1 = *(const short8v*)&Qs[w * 16 + l15][32 + l16 * 8];

  for (int kt = 0; kt < 16; kt += 2) {
    if (kt + 1 < 16) LOADT(kt + 1);
    COMPUTE(KV0);
    if (kt + 1 < 16) WRT(KV1);
    __syncthreads();
    if (kt + 2 < 16) LOADT(kt + 2);
    COMPUTE(KV1);
    if (kt + 2 < 16) WRT(KV0);
    __syncthreads();
  }
#undef LOADT
#undef WRT
#undef COMPUTE

  float inv[4];
#pragma unroll
  for (int r = 0; r < 4; ++r) inv[r] = 1.f / lrun[r];
#pragma unroll
  for (int fd = 0; fd < 3; ++fd)
#pragma unroll
    for (int r = 0; r < 4; ++r) {
      int qrow = qt * 64 + w * 16 + l16 * 4 + r;
      ao[base + (long)qrow * CDIM + fd * 16 + l15] = f2bf(accO[fd][r] * inv[r]);
    }
}

// ---------------------------------------------------------------------------
extern "C" void kernel_launch(void* const* d_in, const int* in_sizes, int n_in,
                              void* d_out, int out_size, void* d_ws, size_t ws_size,
                              hipStream_t stream) {
  const float* x   = (const float*)d_in[0];
  const float* cw  = (const float*)d_in[1];
  const float* dwq = (const float*)d_in[2];
  const float* dwk = (const float*)d_in[3];
  const float* dwv = (const float*)d_in[4];
  const float* gq  = (const float*)d_in[5];
  const float* bq  = (const float*)d_in[6];
  const float* mq  = (const float*)d_in[7];
  const float* vq  = (const float*)d_in[8];
  const float* gk  = (const float*)d_in[9];
  const float* bk  = (const float*)d_in[10];
  const float* mk  = (const float*)d_in[11];
  const float* vk  = (const float*)d_in[12];
  const float* gv  = (const float*)d_in[13];
  const float* bv  = (const float*)d_in[14];
  const float* mv  = (const float*)d_in[15];
  const float* vv  = (const float*)d_in[16];
  const float* wq  = (const float*)d_in[17];
  const float* wk  = (const float*)d_in[18];
  const float* wv  = (const float*)d_in[19];
  const float* wo  = (const float*)d_in[20];
  const float* bo  = (const float*)d_in[21];
  float* out = (float*)d_out;

  char* wsb = (char*)d_ws;
  const size_t SLOTB = (size_t)NB * NPIX * CDIM * 4;   // 12,582,912 B
  const size_t H = SLOTB / 2;                           // 6,291,456 B
  ushort* xcp = (ushort*)(wsb);
  ushort* q0  = (ushort*)(wsb);
  ushort* k0  = (ushort*)(wsb + H);
  ushort* yc  = (ushort*)(wsb + SLOTB);
  ushort* q1  = (ushort*)(wsb + SLOTB);
  ushort* qc  = (ushort*)(wsb + SLOTB + H);
  ushort* k1  = (ushort*)(wsb + SLOTB + H);
  ushort* kc  = (ushort*)(wsb + 2 * SLOTB);
  ushort* v1  = (ushort*)(wsb + 2 * SLOTB);
  ushort* vc  = (ushort*)(wsb + 2 * SLOTB + H);
  ushort* vtp = (ushort*)(wsb + 2 * SLOTB + H);
  ushort* v0  = (ushort*)(wsb + 3 * SLOTB);
  ushort* ao  = (ushort*)(wsb + 3 * SLOTB);
  ushort* wqb = (ushort*)(wsb + 3 * SLOTB + H);
  ushort* wkb = wqb + CDIM * CDIM;
  ushort* wvb = wkb + CDIM * CDIM;
  ushort* wob = wvb + CDIM * CDIM;
  ushort* tbl = wob + CDIM * CDIM;                      // 5*1024 ushorts

  tables_k<<<dim3(20), 256, 0, stream>>>(tbl);
  wconv_k<<<dim3(144), 256, 0, stream>>>(wq, wk, wv, wo, wqb, wkb, wvb, wob);
  xtrans_k<<<dim3(NB, 12, 8), 256, 0, stream>>>(x, xcp);
  fft_conv_k<<<dim3(NB * CDIM), 256, 0, stream>>>(xcp, cw, tbl, dwq, dwk, dwv,
      gq, bq, mq, vq, gk, bk, mk, vk, gv, bv, mv, vv, yc, qc, kc, vc);
  trans_k<<<dim3(NB, 12, 8), 256, 0, stream>>>(yc, qc, kc, vc, out, q0, k0, v0);
  gemm_qkv_k<<<dim3(64, 3, 3), 256, 0, stream>>>(q0, k0, v0, wqb, wkb, wvb, q1, k1, v1);
  vtrans_k<<<dim3(64, 16), 256, 0, stream>>>(v1, vtp);
  attn_mfma_k<<<dim3(64, 16), 256, 0, stream>>>(q1, k1, vtp, ao);
  gemm_out_k<<<dim3(64, 3), 256, 0, stream>>>(ao, wob, bo, out);
}

// Round 10
// 153.568 us; speedup vs baseline: 1.0846x; 1.0846x over previous
//
#include <hip/hip_runtime.h>
#include <hip/hip_bf16.h>
#include <cmath>

#define CDIM 384
#define NB 8
#define NPIX 1024

typedef __attribute__((ext_vector_type(8))) short short8v;
typedef __attribute__((ext_vector_type(4))) float float4v;

__device__ __forceinline__ ushort f2bf(float f) {
  union { float f; unsigned u; } v; v.f = f;
  unsigned r = (v.u + 0x7fffu + ((v.u >> 16) & 1u)) >> 16;
  return (ushort)r;
}
__device__ __forceinline__ float bf2f(ushort u) {
  union { unsigned u; float f; } v; v.u = ((unsigned)u) << 16;
  return v.f;
}

// ---------------------------------------------------------------------------
// Kernel 0: bf16 twiddle tables into ws.
// ---------------------------------------------------------------------------
__global__ __launch_bounds__(256) void tables_k(ushort* __restrict__ tbl) {
  int i = blockIdx.x * 256 + threadIdx.x;
  if (i >= 5 * 1024) return;
  int t = i >> 10, j = i & 1023, r = j >> 5, cidx = j & 31;
  float ang = (float)((r * cidx) & 31) * 0.19634954084936207f;
  float val;
  if (t == 0) val = cosf(ang);
  else if (t == 1) val = sinf(ang);
  else if (t == 2) val = -sinf(ang);
  else {
    if (cidx > 16) val = 0.f;
    else {
      float cv = (cidx == 0 || cidx == 16) ? 1.f : 2.f;
      val = (t == 3) ? cv * cosf(ang) : -cv * sinf(ang);
    }
  }
  tbl[i] = f2bf(val);
}

// ---------------------------------------------------------------------------
// Kernel 0b: x (b,n,c) f32 -> xc (b,c,n) bf16.  LDS tile, both sides coalesced.
// ---------------------------------------------------------------------------
__global__ __launch_bounds__(256) void xtrans_k(
    const float* __restrict__ x, ushort* __restrict__ xc)
{
  const int b = blockIdx.x, c0 = blockIdx.y * 32, n0 = blockIdx.z * 128;
  __shared__ ushort T[128][33];
  for (int i = threadIdx.x; i < 4096; i += 256) {
    int n = i >> 5, c = i & 31;
    T[n][c] = f2bf(x[((long)(b * 1024 + n0 + n)) * CDIM + c0 + c]);
  }
  __syncthreads();
  for (int i = threadIdx.x; i < 4096; i += 256) {
    int c = i >> 7, n = i & 127;
    xc[((long)(b * CDIM + c0 + c)) * 1024 + n0 + n] = T[n][c];
  }
}

// ---------------------------------------------------------------------------
// Kernel 1: spectral filter via MFMA + FUSED depthwise conv3x3 + BN.
// ---------------------------------------------------------------------------
__global__ __launch_bounds__(256) void fft_conv_k(
    const ushort* __restrict__ xc, const float* __restrict__ cw,
    const ushort* __restrict__ tbl,
    const float* __restrict__ dwq, const float* __restrict__ dwk, const float* __restrict__ dwv,
    const float* __restrict__ gq, const float* __restrict__ bq, const float* __restrict__ mq, const float* __restrict__ vq,
    const float* __restrict__ gk, const float* __restrict__ bk, const float* __restrict__ mk, const float* __restrict__ vk,
    const float* __restrict__ gv, const float* __restrict__ bv, const float* __restrict__ mv, const float* __restrict__ vv,
    ushort* __restrict__ yc,
    ushort* __restrict__ qc, ushort* __restrict__ kc, ushort* __restrict__ vc)
{
  const int b = blockIdx.x / CDIM, c = blockIdx.x % CDIM;
  const int tid = threadIdx.x;
  const int w = tid >> 6, lane = tid & 63;
  const int l15 = lane & 15, l16 = lane >> 4;
  __shared__ ushort B[11][32][40];
  __shared__ float Ysf[32][33];

  float wq9[9], wk9[9], wv9[9];
#pragma unroll
  for (int t = 0; t < 9; ++t) {
    wq9[t] = dwq[c * 9 + t];
    wk9[t] = dwk[c * 9 + t];
    wv9[t] = dwv[c * 9 + t];
  }
  float scq = gq[c] * rsqrtf(vq[c] + 1e-5f); float shq = bq[c] - mq[c] * scq;
  float sck = gk[c] * rsqrtf(vk[c] + 1e-5f); float shk = bk[c] - mk[c] * sck;
  float scv = gv[c] * rsqrtf(vv[c] + 1e-5f); float shv = bv[c] - mv[c] * scv;

  for (int i = tid; i < 640; i += 256) {                 // tables -> LDS
    int t = i >> 7, j = i & 127, r = j >> 2, s = j & 3;
    *(uint4*)&B[t][r][s * 8] = *(const uint4*)&tbl[t * 1024 + r * 32 + s * 8];
  }
  for (int i = tid; i < 1024; i += 256)                  // input -> Xt[w][h]
    B[5][i & 31][i >> 5] = xc[(long)(b * CDIM + c) * 1024 + i];
  __syncthreads();

  // stage1: R1[u,w] = sum_h Tc[u,h]*Xt[w,h];  I1 = sum_h Tsn[u,h]*Xt[w,h]
  for (int j = w; j < 8; j += 4) {
    int o = j & 1, ut = (j >> 1) & 1, wt = (j >> 2) & 1;
    short8v af = *(const short8v*)&B[o == 0 ? 0 : 2][ut * 16 + l15][l16 * 8];
    short8v bf = *(const short8v*)&B[5][wt * 16 + l15][l16 * 8];
    float4v acc = {0.f, 0.f, 0.f, 0.f};
    acc = __builtin_amdgcn_mfma_f32_16x16x32_bf16(af, bf, acc, 0, 0, 0);
    int dst = (o == 0) ? 7 : 8;
#pragma unroll
    for (int r = 0; r < 4; ++r)
      B[dst][ut * 16 + l16 * 4 + r][wt * 16 + l15] = f2bf(acc[r]);
  }
  __syncthreads();

  // stage2: Xfr[u,v] = R1.Tc + I1.Ts ; Xfi = I1.Tc + R1.Tsn  (fp32 raw store)
  for (int j = w; j < 8; j += 4) {
    int o = j & 1, ut = (j >> 1) & 1, vt = (j >> 2) & 1;
    short8v a1 = *(const short8v*)&B[o == 0 ? 7 : 8][ut * 16 + l15][l16 * 8];
    short8v b1 = *(const short8v*)&B[0][vt * 16 + l15][l16 * 8];
    short8v a2 = *(const short8v*)&B[o == 0 ? 8 : 7][ut * 16 + l15][l16 * 8];
    short8v b2 = *(const short8v*)&B[o == 0 ? 1 : 2][vt * 16 + l15][l16 * 8];
    float4v acc = {0.f, 0.f, 0.f, 0.f};
    acc = __builtin_amdgcn_mfma_f32_16x16x32_bf16(a1, b1, acc, 0, 0, 0);
    acc = __builtin_amdgcn_mfma_f32_16x16x32_bf16(a2, b2, acc, 0, 0, 0);
    int v = vt * 16 + l15;
    if (v < 17) {
      float* praw = (float*)&B[o == 0 ? 5 : 6][0][0];    // [32][20] f32 view
#pragma unroll
      for (int r = 0; r < 4; ++r)
        praw[(ut * 16 + l16 * 4 + r) * 20 + v] = acc[r];
    }
  }
  __syncthreads();

  // zero Ytr/Yti rows 17..31, then weight-multiply + transpose scatter
  for (int i = tid; i < 150; i += 256) {
    int buf = i / 75, j2 = i % 75, r2 = 17 + j2 / 5, s2 = j2 % 5;
    uint4 z = {0u, 0u, 0u, 0u};
    *(uint4*)&B[9 + buf][r2][s2 * 8] = z;
  }
  {
    const float* xfr = (const float*)&B[5][0][0];
    const float* xfi = (const float*)&B[6][0][0];
    for (int e = tid; e < 544; e += 256) {
      int u = e / 17, v = e - u * 17;
      float fr = xfr[u * 20 + v], fi = xfi[u * 20 + v];
      float2 wc = *(const float2*)&cw[((long)(c * 32 + u) * 17 + v) * 2];
      B[9][v][u]  = f2bf(fr * wc.x - fi * wc.y);
      B[10][v][u] = f2bf(fr * wc.y + fi * wc.x);
    }
  }
  __syncthreads();

  // stage3: Zr[h,v] = Tc(h).Ytr + Tsn(h).Yti ; Zi = Tc(h).Yti + Ts(h).Ytr
  for (int j = w; j < 8; j += 4) {
    int o = j & 1, ht = (j >> 1) & 1, vt = (j >> 2) & 1;
    short8v a1 = *(const short8v*)&B[0][ht * 16 + l15][l16 * 8];
    short8v b1 = *(const short8v*)&B[o == 0 ? 9 : 10][vt * 16 + l15][l16 * 8];
    short8v a2 = *(const short8v*)&B[o == 0 ? 2 : 1][ht * 16 + l15][l16 * 8];
    short8v b2 = *(const short8v*)&B[o == 0 ? 10 : 9][vt * 16 + l15][l16 * 8];
    float4v acc = {0.f, 0.f, 0.f, 0.f};
    acc = __builtin_amdgcn_mfma_f32_16x16x32_bf16(a1, b1, acc, 0, 0, 0);
    acc = __builtin_amdgcn_mfma_f32_16x16x32_bf16(a2, b2, acc, 0, 0, 0);
    int dst = (o == 0) ? 7 : 8;
#pragma unroll
    for (int r = 0; r < 4; ++r)
      B[dst][ht * 16 + l16 * 4 + r][vt * 16 + l15] = f2bf(acc[r]);
  }
  __syncthreads();

  // stage4: y[h,w] = (Zr.Uc^T + Zi.Us^T)/1024 -> Ysf (LDS) + yc (coalesced)
  {
    int ht = w & 1, wt = (w >> 1) & 1;
    short8v a1 = *(const short8v*)&B[7][ht * 16 + l15][l16 * 8];
    short8v b1 = *(const short8v*)&B[3][wt * 16 + l15][l16 * 8];
    short8v a2 = *(const short8v*)&B[8][ht * 16 + l15][l16 * 8];
    short8v b2 = *(const short8v*)&B[4][wt * 16 + l15][l16 * 8];
    float4v acc = {0.f, 0.f, 0.f, 0.f};
    acc = __builtin_amdgcn_mfma_f32_16x16x32_bf16(a1, b1, acc, 0, 0, 0);
    acc = __builtin_amdgcn_mfma_f32_16x16x32_bf16(a2, b2, acc, 0, 0, 0);
#pragma unroll
    for (int r = 0; r < 4; ++r) {
      int hh = ht * 16 + l16 * 4 + r, ww = wt * 16 + l15;
      float y = acc[r] * (1.0f / 1024.0f);
      Ysf[hh][ww] = y;
      yc[(long)(b * CDIM + c) * 1024 + hh * 32 + ww] = f2bf(y);
    }
  }
  __syncthreads();

  // fused depthwise 3x3 conv + BN -> qc/kc/vc (bf16, b,c,n — coalesced)
  for (int i = tid; i < 1024; i += 256) {
    int hh = i >> 5, ww = i & 31;
    float aq = 0.f, ak = 0.f, av = 0.f;
#pragma unroll
    for (int dy = 0; dy < 3; ++dy) {
      int y0 = hh + dy - 1;
#pragma unroll
      for (int dx = 0; dx < 3; ++dx) {
        int x0 = ww + dx - 1;
        float xv = (y0 >= 0 && y0 < 32 && x0 >= 0 && x0 < 32) ? Ysf[y0][x0] : 0.f;
        int t = dy * 3 + dx;
        aq += xv * wq9[t]; ak += xv * wk9[t]; av += xv * wv9[t];
      }
    }
    long o = (long)(b * CDIM + c) * 1024 + i;
    qc[o] = f2bf(aq * scq + shq);
    kc[o] = f2bf(ak * sck + shk);
    vc[o] = f2bf(av * scv + shv);
  }
}

// ---------------------------------------------------------------------------
// Kernel 1b: transpose (b,c,n)->(b,n,c): yc->out (f32), qc/kc/vc->q0/k0/v0.
// ---------------------------------------------------------------------------
__global__ __launch_bounds__(256) void trans_k(
    const ushort* __restrict__ yc, const ushort* __restrict__ qc,
    const ushort* __restrict__ kc, const ushort* __restrict__ vc,
    float* __restrict__ out, ushort* __restrict__ q0,
    ushort* __restrict__ k0, ushort* __restrict__ v0)
{
  const int b = blockIdx.x, c0 = blockIdx.y * 32, n0 = blockIdx.z * 128;
  __shared__ ushort T[128][33];
  const ushort* srcs[4] = {yc, qc, kc, vc};
#pragma unroll
  for (int p = 0; p < 4; ++p) {
    if (p) __syncthreads();
    const ushort* s = srcs[p];
    for (int i = threadIdx.x; i < 4096; i += 256) {
      int c = i >> 7, n = i & 127;
      T[n][c] = s[((long)(b * CDIM + c0 + c)) * 1024 + n0 + n];
    }
    __syncthreads();
    for (int i = threadIdx.x; i < 4096; i += 256) {
      int n = i >> 5, c = i & 31;
      long o = ((long)(b * 1024 + n0 + n)) * CDIM + c0 + c;
      ushort v = T[n][c];
      if (p == 0)      out[o] = bf2f(v);
      else if (p == 1) q0[o] = v;
      else if (p == 2) k0[o] = v;
      else             v0[o] = v;
    }
  }
}

// ---------------------------------------------------------------------------
// Kernel 2b: convert the 4 projection weights to bf16
// ---------------------------------------------------------------------------
__global__ __launch_bounds__(256) void wconv_k(
    const float* __restrict__ a, const float* __restrict__ b,
    const float* __restrict__ c, const float* __restrict__ d,
    ushort* __restrict__ oa, ushort* __restrict__ ob,
    ushort* __restrict__ oc, ushort* __restrict__ od)
{
  int i = blockIdx.x * 256 + threadIdx.x;
  if (i * 4 >= CDIM * CDIM) return;
  float4 va = *(const float4*)&a[i * 4];
  float4 vb = *(const float4*)&b[i * 4];
  float4 vc = *(const float4*)&c[i * 4];
  float4 vd = *(const float4*)&d[i * 4];
  ushort4 ra = { f2bf(va.x), f2bf(va.y), f2bf(va.z), f2bf(va.w) };
  ushort4 rb = { f2bf(vb.x), f2bf(vb.y), f2bf(vb.z), f2bf(vb.w) };
  ushort4 rc = { f2bf(vc.x), f2bf(vc.y), f2bf(vc.z), f2bf(vc.w) };
  ushort4 rd = { f2bf(vd.x), f2bf(vd.y), f2bf(vd.z), f2bf(vd.w) };
  *(ushort4*)&oa[i * 4] = ra;
  *(ushort4*)&ob[i * 4] = rb;
  *(ushort4*)&oc[i * 4] = rc;
  *(ushort4*)&od[i * 4] = rd;
}

// ---------------------------------------------------------------------------
// MFMA GEMM body  C[m,n'] = sum_k A[m,k] W[n',k]
// tile 128x64, BK=64, 4 waves (2x2), padded LDS (stride 72 bf16 = 144B).
// flags==0: bf16 store.  flags==1: fp32 RMW  out += acc + bias.
// ---------------------------------------------------------------------------
__device__ __forceinline__ void gemm_body(
    const ushort* __restrict__ A, const ushort* __restrict__ Wb,
    const float* __restrict__ bias, void* __restrict__ Cd, int flags,
    int bx, int by)
{
  __shared__ ushort As[128][72];
  __shared__ ushort Ws[64][72];
  const int tid = threadIdx.x;
  const int w = tid >> 6, lane = tid & 63;
  const int l15 = lane & 15, l16 = lane >> 4;
  const int wm = w >> 1, wn = w & 1;
  const int row0 = bx * 128, col0 = by * 64;
  float4v acc[4][2];
#pragma unroll
  for (int i = 0; i < 4; ++i)
#pragma unroll
    for (int j = 0; j < 2; ++j) acc[i][j] = (float4v){0.f, 0.f, 0.f, 0.f};
  for (int kt = 0; kt < CDIM; kt += 64) {
    if (kt) __syncthreads();
    for (int c = tid; c < 1024; c += 256) {
      int r = c >> 3, s = c & 7;
      *(uint4*)&As[r][s * 8] = *(const uint4*)&A[(long)(row0 + r) * CDIM + kt + s * 8];
    }
    for (int c = tid; c < 512; c += 256) {
      int r = c >> 3, s = c & 7;
      *(uint4*)&Ws[r][s * 8] = *(const uint4*)&Wb[(long)(col0 + r) * CDIM + kt + s * 8];
    }
    __syncthreads();
#pragma unroll
    for (int s = 0; s < 2; ++s) {
      short8v a[4], bfr[2];
#pragma unroll
      for (int i = 0; i < 4; ++i)
        a[i] = *(const short8v*)&As[wm * 64 + i * 16 + l15][s * 32 + l16 * 8];
#pragma unroll
      for (int j = 0; j < 2; ++j)
        bfr[j] = *(const short8v*)&Ws[wn * 32 + j * 16 + l15][s * 32 + l16 * 8];
#pragma unroll
      for (int i = 0; i < 4; ++i)
#pragma unroll
        for (int j = 0; j < 2; ++j)
          acc[i][j] = __builtin_amdgcn_mfma_f32_16x16x32_bf16(a[i], bfr[j], acc[i][j], 0, 0, 0);
    }
  }
#pragma unroll
  for (int i = 0; i < 4; ++i)
#pragma unroll
    for (int j = 0; j < 2; ++j) {
      int col = col0 + wn * 32 + j * 16 + l15;
      int rbase = row0 + wm * 64 + i * 16 + l16 * 4;
#pragma unroll
      for (int r = 0; r < 4; ++r) {
        long o = (long)(rbase + r) * CDIM + col;
        if (flags == 0) ((ushort*)Cd)[o] = f2bf(acc[i][j][r]);
        else            ((float*)Cd)[o] += acc[i][j][r] + bias[col];
      }
    }
}

// fused q/k/v projection GEMMs (blockIdx.z selects)
__global__ __launch_bounds__(256) void gemm_qkv_k(
    const ushort* __restrict__ q0, const ushort* __restrict__ k0, const ushort* __restrict__ v0,
    const ushort* __restrict__ wqb, const ushort* __restrict__ wkb, const ushort* __restrict__ wvb,
    ushort* __restrict__ q1, ushort* __restrict__ k1, ushort* __restrict__ v1)
{
  const int z = blockIdx.z;
  const ushort* A  = z == 0 ? q0  : z == 1 ? k0  : v0;
  const ushort* Wb = z == 0 ? wqb : z == 1 ? wkb : wvb;
  ushort*       C  = z == 0 ? q1  : z == 1 ? k1  : v1;
  gemm_body(A, Wb, nullptr, C, 0, blockIdx.x, blockIdx.y);
}

// final projection: out += A@wo^T + bo
__global__ __launch_bounds__(256) void gemm_out_k(
    const ushort* __restrict__ A, const ushort* __restrict__ Wb,
    const float* __restrict__ bias, float* __restrict__ Cd)
{
  gemm_body(A, Wb, bias, Cd, 1, blockIdx.x, blockIdx.y);
}

// ---------------------------------------------------------------------------
// Kernel 3b: V transpose  v1 (b,n,h*48+d) -> vt ((b*8+h)*48+d, n)
// ---------------------------------------------------------------------------
__global__ __launch_bounds__(256) void vtrans_k(
    const ushort* __restrict__ v1, ushort* __restrict__ vt)
{
  const int bh = blockIdx.x, b = bh >> 3, h = bh & 7;
  const int n0 = blockIdx.y * 64;
  const int tid = threadIdx.x;
  __shared__ unsigned Lu[64][49];
  for (int i = tid; i < 384; i += 256) {
    int r = i / 6, s = i - r * 6;
    uint4 p = *(const uint4*)&v1[(long)(b * 1024 + n0 + r) * CDIM + h * 48 + s * 8];
    unsigned d0 = s * 8;
    Lu[r][d0 + 0] = p.x & 0xffffu;        Lu[r][d0 + 1] = p.x >> 16;
    Lu[r][d0 + 2] = p.y & 0xffffu;        Lu[r][d0 + 3] = p.y >> 16;
    Lu[r][d0 + 4] = p.z & 0xffffu;        Lu[r][d0 + 5] = p.z >> 16;
    Lu[r][d0 + 6] = p.w & 0xffffu;        Lu[r][d0 + 7] = p.w >> 16;
  }
  __syncthreads();
  for (int i = tid; i < 384; i += 256) {
    int d = i >> 3, s = i & 7;
    uint4 o;
    o.x = Lu[s * 8 + 0][d] | (Lu[s * 8 + 1][d] << 16);
    o.y = Lu[s * 8 + 2][d] | (Lu[s * 8 + 3][d] << 16);
    o.z = Lu[s * 8 + 4][d] | (Lu[s * 8 + 5][d] << 16);
    o.w = Lu[s * 8 + 6][d] | (Lu[s * 8 + 7][d] << 16);
    *(uint4*)&vt[((long)bh * 48 + d) * NPIX + n0 + s * 8] = o;
  }
}

// ---------------------------------------------------------------------------
// Kernel 4: MFMA flash attention.
//  - r7 single-buffer staging structure (2 barriers/iter, lowest LDS)
//  - SWAPPED QK^T: sacc = mfma(K, Q) = S^T, so lane holds 4 consecutive k
//    per fragment -> P packed with v_cvt_pk_bf16_f32 (via __float22bfloat162)
//    and written as 8 ds_write_b32 (was 16 f2bf + 16 ds_write_b16)
//  - Q fragments loaded directly from global (no Qs LDS): LDS 25.3 KB
//  - no-max softmax + ones-MFMA row sums
// ---------------------------------------------------------------------------
__global__ __launch_bounds__(256) void attn_mfma_k(
    const ushort* __restrict__ q1, const ushort* __restrict__ k1,
    const ushort* __restrict__ vt, ushort* __restrict__ ao)
{
  const int bh = blockIdx.x, qt = blockIdx.y;
  const int b = bh >> 3, h = bh & 7;
  const int tid = threadIdx.x;
  const int w = tid >> 6, lane = tid & 63;
  const int l15 = lane & 15, l16 = lane >> 4;
  __shared__ ushort Ks[64][72], Vs[48][72], Ps[64][72];
  const float scale = 0.051031036307982884f;  // 384^-0.5
  const long base = (long)b * NPIX * CDIM + h * 48;
  const long vbase = (long)bh * 48 * NPIX;

  // zero K pad (cols 48..63), persists across iterations
  if (tid < 128) {
    uint4 z4 = {0u, 0u, 0u, 0u};
    int r = tid >> 1, s = tid & 1;
    *(uint4*)&Ks[r][48 + s * 8] = z4;
  }
  // Q fragments direct from global; d=48..63 lanes -> zero
  const long qrow = base + (long)(qt * 64 + w * 16 + l15) * CDIM;
  short8v qa0 = *(const short8v*)&q1[qrow + l16 * 8];
  short8v qa1;
  {
    short8v qz = {};
    short8v qv = *(const short8v*)&q1[qrow + ((l16 < 2) ? 32 + l16 * 8 : 0)];
    qa1 = (l16 < 2) ? qv : qz;
  }

  float lrun[4] = {0.f, 0.f, 0.f, 0.f};
  float4v accO[3];
#pragma unroll
  for (int fd = 0; fd < 3; ++fd) accO[fd] = (float4v){0.f, 0.f, 0.f, 0.f};
  short8v onesb;
#pragma unroll
  for (int j = 0; j < 8; ++j) onesb[j] = (short)0x3F80;  // bf16 1.0

  for (int kt = 0; kt < 16; ++kt) {
    if (kt) __syncthreads();
    for (int i = tid; i < 768; i += 256) {
      if (i < 384) {
        int r = i / 6, s = i - r * 6;
        *(uint4*)&Ks[r][s * 8] = *(const uint4*)&k1[base + (long)(kt * 64 + r) * CDIM + s * 8];
      } else {
        int j = i - 384, d = j >> 3, s = j & 7;
        *(uint4*)&Vs[d][s * 8] = *(const uint4*)&vt[vbase + (long)d * NPIX + kt * 64 + s * 8];
      }
    }
    __syncthreads();
    // swapped QK^T: S^T[k][q]; lane q = l15, k = fc*16 + l16*4 + r
    float4v sacc[4];
#pragma unroll
    for (int fc = 0; fc < 4; ++fc) {
      short8v kb0 = *(const short8v*)&Ks[fc * 16 + l15][l16 * 8];
      short8v kb1 = *(const short8v*)&Ks[fc * 16 + l15][32 + l16 * 8];
      sacc[fc] = (float4v){0.f, 0.f, 0.f, 0.f};
      sacc[fc] = __builtin_amdgcn_mfma_f32_16x16x32_bf16(kb0, qa0, sacc[fc], 0, 0, 0);
      sacc[fc] = __builtin_amdgcn_mfma_f32_16x16x32_bf16(kb1, qa1, sacc[fc], 0, 0, 0);
    }
    // P = exp(S*scale); pack pairs of consecutive k -> dword stores
    // row (q) = w*16 + l15 is wave-private
    unsigned* prow = (unsigned*)&Ps[w * 16 + l15][0];
#pragma unroll
    for (int fc = 0; fc < 4; ++fc) {
      float p0 = __expf(sacc[fc][0] * scale);
      float p1 = __expf(sacc[fc][1] * scale);
      float p2 = __expf(sacc[fc][2] * scale);
      float p3 = __expf(sacc[fc][3] * scale);
      __hip_bfloat162 d01 = __float22bfloat162_rn(make_float2(p0, p1));
      __hip_bfloat162 d23 = __float22bfloat162_rn(make_float2(p2, p3));
      prow[fc * 8 + l16 * 2 + 0] = *(unsigned*)&d01;
      prow[fc * 8 + l16 * 2 + 1] = *(unsigned*)&d23;
    }
    // Ps is wave-private: intra-wave DS drain, no block barrier
    asm volatile("s_waitcnt lgkmcnt(0)" ::: "memory");
    __builtin_amdgcn_sched_barrier(0);
    short8v pa0 = *(const short8v*)&Ps[w * 16 + l15][l16 * 8];
    short8v pa1 = *(const short8v*)&Ps[w * 16 + l15][32 + l16 * 8];
    // row sums via ones-MFMA (matrix pipe, reuses pa fragments)
    float4v srow = (float4v){0.f, 0.f, 0.f, 0.f};
    srow = __builtin_amdgcn_mfma_f32_16x16x32_bf16(pa0, onesb, srow, 0, 0, 0);
    srow = __builtin_amdgcn_mfma_f32_16x16x32_bf16(pa1, onesb, srow, 0, 0, 0);
#pragma unroll
    for (int r = 0; r < 4; ++r) lrun[r] += srow[r];
    // PV: O(16x48) += P(16x64) . V(64x48)
#pragma unroll
    for (int fd = 0; fd < 3; ++fd) {
      short8v vb0 = *(const short8v*)&Vs[fd * 16 + l15][l16 * 8];
      short8v vb1 = *(const short8v*)&Vs[fd * 16 + l15][32 + l16 * 8];
      accO[fd] = __builtin_amdgcn_mfma_f32_16x16x32_bf16(pa0, vb0, accO[fd], 0, 0, 0);
      accO[fd] = __builtin_amdgcn_mfma_f32_16x16x32_bf16(pa1, vb1, accO[fd], 0, 0, 0);
    }
  }
  float inv[4];
#pragma unroll
  for (int r = 0; r < 4; ++r) inv[r] = 1.f / lrun[r];
#pragma unroll
  for (int fd = 0; fd < 3; ++fd)
#pragma unroll
    for (int r = 0; r < 4; ++r) {
      int qrow2 = qt * 64 + w * 16 + l16 * 4 + r;
      ao[base + (long)qrow2 * CDIM + fd * 16 + l15] = f2bf(accO[fd][r] * inv[r]);
    }
}

// ---------------------------------------------------------------------------
extern "C" void kernel_launch(void* const* d_in, const int* in_sizes, int n_in,
                              void* d_out, int out_size, void* d_ws, size_t ws_size,
                              hipStream_t stream) {
  const float* x   = (const float*)d_in[0];
  const float* cw  = (const float*)d_in[1];
  const float* dwq = (const float*)d_in[2];
  const float* dwk = (const float*)d_in[3];
  const float* dwv = (const float*)d_in[4];
  const float* gq  = (const float*)d_in[5];
  const float* bq  = (const float*)d_in[6];
  const float* mq  = (const float*)d_in[7];
  const float* vq  = (const float*)d_in[8];
  const float* gk  = (const float*)d_in[9];
  const float* bk  = (const float*)d_in[10];
  const float* mk  = (const float*)d_in[11];
  const float* vk  = (const float*)d_in[12];
  const float* gv  = (const float*)d_in[13];
  const float* bv  = (const float*)d_in[14];
  const float* mv  = (const float*)d_in[15];
  const float* vv  = (const float*)d_in[16];
  const float* wq  = (const float*)d_in[17];
  const float* wk  = (const float*)d_in[18];
  const float* wv  = (const float*)d_in[19];
  const float* wo  = (const float*)d_in[20];
  const float* bo  = (const float*)d_in[21];
  float* out = (float*)d_out;

  char* wsb = (char*)d_ws;
  const size_t SLOTB = (size_t)NB * NPIX * CDIM * 4;   // 12,582,912 B
  const size_t H = SLOTB / 2;                           // 6,291,456 B
  ushort* xcp = (ushort*)(wsb);
  ushort* q0  = (ushort*)(wsb);
  ushort* k0  = (ushort*)(wsb + H);
  ushort* yc  = (ushort*)(wsb + SLOTB);
  ushort* q1  = (ushort*)(wsb + SLOTB);
  ushort* qc  = (ushort*)(wsb + SLOTB + H);
  ushort* k1  = (ushort*)(wsb + SLOTB + H);
  ushort* kc  = (ushort*)(wsb + 2 * SLOTB);
  ushort* v1  = (ushort*)(wsb + 2 * SLOTB);
  ushort* vc  = (ushort*)(wsb + 2 * SLOTB + H);
  ushort* vtp = (ushort*)(wsb + 2 * SLOTB + H);
  ushort* v0  = (ushort*)(wsb + 3 * SLOTB);
  ushort* ao  = (ushort*)(wsb + 3 * SLOTB);
  ushort* wqb = (ushort*)(wsb + 3 * SLOTB + H);
  ushort* wkb = wqb + CDIM * CDIM;
  ushort* wvb = wkb + CDIM * CDIM;
  ushort* wob = wvb + CDIM * CDIM;
  ushort* tbl = wob + CDIM * CDIM;                      // 5*1024 ushorts

  tables_k<<<dim3(20), 256, 0, stream>>>(tbl);
  wconv_k<<<dim3(144), 256, 0, stream>>>(wq, wk, wv, wo, wqb, wkb, wvb, wob);
  xtrans_k<<<dim3(NB, 12, 8), 256, 0, stream>>>(x, xcp);
  fft_conv_k<<<dim3(NB * CDIM), 256, 0, stream>>>(xcp, cw, tbl, dwq, dwk, dwv,
      gq, bq, mq, vq, gk, bk, mk, vk, gv, bv, mv, vv, yc, qc, kc, vc);
  trans_k<<<dim3(NB, 12, 8), 256, 0, stream>>>(yc, qc, kc, vc, out, q0, k0, v0);
  gemm_qkv_k<<<dim3(64, 6, 3), 256, 0, stream>>>(q0, k0, v0, wqb, wkb, wvb, q1, k1, v1);
  vtrans_k<<<dim3(64, 16), 256, 0, stream>>>(v1, vtp);
  attn_mfma_k<<<dim3(64, 16), 256, 0, stream>>>(q1, k1, vtp, ao);
  gemm_out_k<<<dim3(64, 6), 256, 0, stream>>>(ao, wob, bo, out);
}

// Round 11
// 140.572 us; speedup vs baseline: 1.1849x; 1.0924x over previous
//
#include <hip/hip_runtime.h>
#include <hip/hip_bf16.h>
#include <cmath>

#define CDIM 384
#define NB 8
#define NPIX 1024

typedef __attribute__((ext_vector_type(8))) short short8v;
typedef __attribute__((ext_vector_type(4))) float float4v;

__device__ __forceinline__ ushort f2bf(float f) {
  union { float f; unsigned u; } v; v.f = f;
  unsigned r = (v.u + 0x7fffu + ((v.u >> 16) & 1u)) >> 16;
  return (ushort)r;
}
__device__ __forceinline__ float bf2f(ushort u) {
  union { unsigned u; float f; } v; v.u = ((unsigned)u) << 16;
  return v.f;
}

// ---------------------------------------------------------------------------
// Kernel 0: bf16 twiddle tables + projection-weight bf16 conversion (merged).
// blocks 0..19: tables (5*1024 entries).  blocks 20..163: weight conversion.
// ---------------------------------------------------------------------------
__global__ __launch_bounds__(256) void prep_k(
    ushort* __restrict__ tbl,
    const float* __restrict__ wq, const float* __restrict__ wk,
    const float* __restrict__ wv, const float* __restrict__ wo,
    ushort* __restrict__ wqb, ushort* __restrict__ wkb,
    ushort* __restrict__ wvb, ushort* __restrict__ wob)
{
  if (blockIdx.x < 20) {
    int i = blockIdx.x * 256 + threadIdx.x;
    if (i >= 5 * 1024) return;
    int t = i >> 10, j = i & 1023, r = j >> 5, cidx = j & 31;
    float ang = (float)((r * cidx) & 31) * 0.19634954084936207f;
    float val;
    if (t == 0) val = cosf(ang);
    else if (t == 1) val = sinf(ang);
    else if (t == 2) val = -sinf(ang);
    else {
      if (cidx > 16) val = 0.f;
      else {
        float cv = (cidx == 0 || cidx == 16) ? 1.f : 2.f;
        val = (t == 3) ? cv * cosf(ang) : -cv * sinf(ang);
      }
    }
    tbl[i] = f2bf(val);
  } else {
    int i = (blockIdx.x - 20) * 256 + threadIdx.x;
    if (i * 4 >= CDIM * CDIM) return;
    float4 va = *(const float4*)&wq[i * 4];
    float4 vb = *(const float4*)&wk[i * 4];
    float4 vc = *(const float4*)&wv[i * 4];
    float4 vd = *(const float4*)&wo[i * 4];
    ushort4 ra = { f2bf(va.x), f2bf(va.y), f2bf(va.z), f2bf(va.w) };
    ushort4 rb = { f2bf(vb.x), f2bf(vb.y), f2bf(vb.z), f2bf(vb.w) };
    ushort4 rc = { f2bf(vc.x), f2bf(vc.y), f2bf(vc.z), f2bf(vc.w) };
    ushort4 rd = { f2bf(vd.x), f2bf(vd.y), f2bf(vd.z), f2bf(vd.w) };
    *(ushort4*)&wqb[i * 4] = ra;
    *(ushort4*)&wkb[i * 4] = rb;
    *(ushort4*)&wvb[i * 4] = rc;
    *(ushort4*)&wob[i * 4] = rd;
  }
}

// ---------------------------------------------------------------------------
// Kernel 0b: x (b,n,c) f32 -> xc (b,c,n) bf16.
// ---------------------------------------------------------------------------
__global__ __launch_bounds__(256) void xtrans_k(
    const float* __restrict__ x, ushort* __restrict__ xc)
{
  const int b = blockIdx.x, c0 = blockIdx.y * 32, n0 = blockIdx.z * 128;
  __shared__ ushort T[128][33];
  for (int i = threadIdx.x; i < 4096; i += 256) {
    int n = i >> 5, c = i & 31;
    T[n][c] = f2bf(x[((long)(b * 1024 + n0 + n)) * CDIM + c0 + c]);
  }
  __syncthreads();
  for (int i = threadIdx.x; i < 4096; i += 256) {
    int c = i >> 7, n = i & 127;
    xc[((long)(b * CDIM + c0 + c)) * 1024 + n0 + n] = T[n][c];
  }
}

// ---------------------------------------------------------------------------
// Kernel 1: spectral filter via MFMA + FUSED depthwise conv3x3 + BN.
// ---------------------------------------------------------------------------
__global__ __launch_bounds__(256) void fft_conv_k(
    const ushort* __restrict__ xc, const float* __restrict__ cw,
    const ushort* __restrict__ tbl,
    const float* __restrict__ dwq, const float* __restrict__ dwk, const float* __restrict__ dwv,
    const float* __restrict__ gq, const float* __restrict__ bq, const float* __restrict__ mq, const float* __restrict__ vq,
    const float* __restrict__ gk, const float* __restrict__ bk, const float* __restrict__ mk, const float* __restrict__ vk,
    const float* __restrict__ gv, const float* __restrict__ bv, const float* __restrict__ mv, const float* __restrict__ vv,
    ushort* __restrict__ yc,
    ushort* __restrict__ qc, ushort* __restrict__ kc, ushort* __restrict__ vc)
{
  const int b = blockIdx.x / CDIM, c = blockIdx.x % CDIM;
  const int tid = threadIdx.x;
  const int w = tid >> 6, lane = tid & 63;
  const int l15 = lane & 15, l16 = lane >> 4;
  __shared__ ushort B[11][32][40];
  __shared__ float Ysf[32][33];

  float wq9[9], wk9[9], wv9[9];
#pragma unroll
  for (int t = 0; t < 9; ++t) {
    wq9[t] = dwq[c * 9 + t];
    wk9[t] = dwk[c * 9 + t];
    wv9[t] = dwv[c * 9 + t];
  }
  float scq = gq[c] * rsqrtf(vq[c] + 1e-5f); float shq = bq[c] - mq[c] * scq;
  float sck = gk[c] * rsqrtf(vk[c] + 1e-5f); float shk = bk[c] - mk[c] * sck;
  float scv = gv[c] * rsqrtf(vv[c] + 1e-5f); float shv = bv[c] - mv[c] * scv;

  for (int i = tid; i < 640; i += 256) {                 // tables -> LDS
    int t = i >> 7, j = i & 127, r = j >> 2, s = j & 3;
    *(uint4*)&B[t][r][s * 8] = *(const uint4*)&tbl[t * 1024 + r * 32 + s * 8];
  }
  for (int i = tid; i < 1024; i += 256)                  // input -> Xt[w][h]
    B[5][i & 31][i >> 5] = xc[(long)(b * CDIM + c) * 1024 + i];
  __syncthreads();

  // stage1: R1[u,w] = sum_h Tc[u,h]*Xt[w,h];  I1 = sum_h Tsn[u,h]*Xt[w,h]
  for (int j = w; j < 8; j += 4) {
    int o = j & 1, ut = (j >> 1) & 1, wt = (j >> 2) & 1;
    short8v af = *(const short8v*)&B[o == 0 ? 0 : 2][ut * 16 + l15][l16 * 8];
    short8v bf = *(const short8v*)&B[5][wt * 16 + l15][l16 * 8];
    float4v acc = {0.f, 0.f, 0.f, 0.f};
    acc = __builtin_amdgcn_mfma_f32_16x16x32_bf16(af, bf, acc, 0, 0, 0);
    int dst = (o == 0) ? 7 : 8;
#pragma unroll
    for (int r = 0; r < 4; ++r)
      B[dst][ut * 16 + l16 * 4 + r][wt * 16 + l15] = f2bf(acc[r]);
  }
  __syncthreads();

  // stage2: Xfr[u,v] = R1.Tc + I1.Ts ; Xfi = I1.Tc + R1.Tsn  (fp32 raw store)
  for (int j = w; j < 8; j += 4) {
    int o = j & 1, ut = (j >> 1) & 1, vt = (j >> 2) & 1;
    short8v a1 = *(const short8v*)&B[o == 0 ? 7 : 8][ut * 16 + l15][l16 * 8];
    short8v b1 = *(const short8v*)&B[0][vt * 16 + l15][l16 * 8];
    short8v a2 = *(const short8v*)&B[o == 0 ? 8 : 7][ut * 16 + l15][l16 * 8];
    short8v b2 = *(const short8v*)&B[o == 0 ? 1 : 2][vt * 16 + l15][l16 * 8];
    float4v acc = {0.f, 0.f, 0.f, 0.f};
    acc = __builtin_amdgcn_mfma_f32_16x16x32_bf16(a1, b1, acc, 0, 0, 0);
    acc = __builtin_amdgcn_mfma_f32_16x16x32_bf16(a2, b2, acc, 0, 0, 0);
    int v = vt * 16 + l15;
    if (v < 17) {
      float* praw = (float*)&B[o == 0 ? 5 : 6][0][0];    // [32][20] f32 view
#pragma unroll
      for (int r = 0; r < 4; ++r)
        praw[(ut * 16 + l16 * 4 + r) * 20 + v] = acc[r];
    }
  }
  __syncthreads();

  // zero Ytr/Yti rows 17..31, then weight-multiply + transpose scatter
  for (int i = tid; i < 150; i += 256) {
    int buf = i / 75, j2 = i % 75, r2 = 17 + j2 / 5, s2 = j2 % 5;
    uint4 z = {0u, 0u, 0u, 0u};
    *(uint4*)&B[9 + buf][r2][s2 * 8] = z;
  }
  {
    const float* xfr = (const float*)&B[5][0][0];
    const float* xfi = (const float*)&B[6][0][0];
    for (int e = tid; e < 544; e += 256) {
      int u = e / 17, v = e - u * 17;
      float fr = xfr[u * 20 + v], fi = xfi[u * 20 + v];
      float2 wc = *(const float2*)&cw[((long)(c * 32 + u) * 17 + v) * 2];
      B[9][v][u]  = f2bf(fr * wc.x - fi * wc.y);
      B[10][v][u] = f2bf(fr * wc.y + fi * wc.x);
    }
  }
  __syncthreads();

  // stage3: Zr[h,v] = Tc(h).Ytr + Tsn(h).Yti ; Zi = Tc(h).Yti + Ts(h).Ytr
  for (int j = w; j < 8; j += 4) {
    int o = j & 1, ht = (j >> 1) & 1, vt = (j >> 2) & 1;
    short8v a1 = *(const short8v*)&B[0][ht * 16 + l15][l16 * 8];
    short8v b1 = *(const short8v*)&B[o == 0 ? 9 : 10][vt * 16 + l15][l16 * 8];
    short8v a2 = *(const short8v*)&B[o == 0 ? 2 : 1][ht * 16 + l15][l16 * 8];
    short8v b2 = *(const short8v*)&B[o == 0 ? 10 : 9][vt * 16 + l15][l16 * 8];
    float4v acc = {0.f, 0.f, 0.f, 0.f};
    acc = __builtin_amdgcn_mfma_f32_16x16x32_bf16(a1, b1, acc, 0, 0, 0);
    acc = __builtin_amdgcn_mfma_f32_16x16x32_bf16(a2, b2, acc, 0, 0, 0);
    int dst = (o == 0) ? 7 : 8;
#pragma unroll
    for (int r = 0; r < 4; ++r)
      B[dst][ht * 16 + l16 * 4 + r][vt * 16 + l15] = f2bf(acc[r]);
  }
  __syncthreads();

  // stage4: y[h,w] = (Zr.Uc^T + Zi.Us^T)/1024 -> Ysf (LDS) + yc (coalesced)
  {
    int ht = w & 1, wt = (w >> 1) & 1;
    short8v a1 = *(const short8v*)&B[7][ht * 16 + l15][l16 * 8];
    short8v b1 = *(const short8v*)&B[3][wt * 16 + l15][l16 * 8];
    short8v a2 = *(const short8v*)&B[8][ht * 16 + l15][l16 * 8];
    short8v b2 = *(const short8v*)&B[4][wt * 16 + l15][l16 * 8];
    float4v acc = {0.f, 0.f, 0.f, 0.f};
    acc = __builtin_amdgcn_mfma_f32_16x16x32_bf16(a1, b1, acc, 0, 0, 0);
    acc = __builtin_amdgcn_mfma_f32_16x16x32_bf16(a2, b2, acc, 0, 0, 0);
#pragma unroll
    for (int r = 0; r < 4; ++r) {
      int hh = ht * 16 + l16 * 4 + r, ww = wt * 16 + l15;
      float y = acc[r] * (1.0f / 1024.0f);
      Ysf[hh][ww] = y;
      yc[(long)(b * CDIM + c) * 1024 + hh * 32 + ww] = f2bf(y);
    }
  }
  __syncthreads();

  // fused depthwise 3x3 conv + BN -> qc/kc/vc (bf16, b,c,n — coalesced)
  for (int i = tid; i < 1024; i += 256) {
    int hh = i >> 5, ww = i & 31;
    float aq = 0.f, ak = 0.f, av = 0.f;
#pragma unroll
    for (int dy = 0; dy < 3; ++dy) {
      int y0 = hh + dy - 1;
#pragma unroll
      for (int dx = 0; dx < 3; ++dx) {
        int x0 = ww + dx - 1;
        float xv = (y0 >= 0 && y0 < 32 && x0 >= 0 && x0 < 32) ? Ysf[y0][x0] : 0.f;
        int t = dy * 3 + dx;
        aq += xv * wq9[t]; ak += xv * wk9[t]; av += xv * wv9[t];
      }
    }
    long o = (long)(b * CDIM + c) * 1024 + i;
    qc[o] = f2bf(aq * scq + shq);
    kc[o] = f2bf(ak * sck + shk);
    vc[o] = f2bf(av * scv + shv);
  }
}

// ---------------------------------------------------------------------------
// Kernel 1b: transpose (b,c,n)->(b,n,c) for qc/kc/vc -> q0/k0/v0 (bf16).
// (x_fft residual is now applied inside gemm_out from yc directly.)
// ---------------------------------------------------------------------------
__global__ __launch_bounds__(256) void trans_k(
    const ushort* __restrict__ qc, const ushort* __restrict__ kc,
    const ushort* __restrict__ vc,
    ushort* __restrict__ q0, ushort* __restrict__ k0, ushort* __restrict__ v0)
{
  const int b = blockIdx.x, c0 = blockIdx.y * 32, n0 = blockIdx.z * 128;
  __shared__ ushort T[128][33];
  const ushort* srcs[3] = {qc, kc, vc};
#pragma unroll
  for (int p = 0; p < 3; ++p) {
    if (p) __syncthreads();
    const ushort* s = srcs[p];
    for (int i = threadIdx.x; i < 4096; i += 256) {
      int c = i >> 7, n = i & 127;
      T[n][c] = s[((long)(b * CDIM + c0 + c)) * 1024 + n0 + n];
    }
    __syncthreads();
    for (int i = threadIdx.x; i < 4096; i += 256) {
      int n = i >> 5, c = i & 31;
      long o = ((long)(b * 1024 + n0 + n)) * CDIM + c0 + c;
      ushort v = T[n][c];
      if (p == 0)      q0[o] = v;
      else if (p == 1) k0[o] = v;
      else             v0[o] = v;
    }
  }
}

// ---------------------------------------------------------------------------
// MFMA GEMM body  C[m,n'] = sum_k A[m,k] W[n',k]
// tile 128x64, BK=64, 4 waves (2x2), padded LDS (stride 72 bf16 = 144B).
// flags==0: bf16 store.  flags==1: fp32 write  out = acc + bias + y(residual
// read from ycr, (b,c,n) bf16 layout).
// ---------------------------------------------------------------------------
__device__ __forceinline__ void gemm_body(
    const ushort* __restrict__ A, const ushort* __restrict__ Wb,
    const float* __restrict__ bias, const ushort* __restrict__ ycr,
    void* __restrict__ Cd, int flags, int bx, int by)
{
  __shared__ ushort As[128][72];
  __shared__ ushort Ws[64][72];
  const int tid = threadIdx.x;
  const int w = tid >> 6, lane = tid & 63;
  const int l15 = lane & 15, l16 = lane >> 4;
  const int wm = w >> 1, wn = w & 1;
  const int row0 = bx * 128, col0 = by * 64;
  float4v acc[4][2];
#pragma unroll
  for (int i = 0; i < 4; ++i)
#pragma unroll
    for (int j = 0; j < 2; ++j) acc[i][j] = (float4v){0.f, 0.f, 0.f, 0.f};
  for (int kt = 0; kt < CDIM; kt += 64) {
    if (kt) __syncthreads();
    for (int c = tid; c < 1024; c += 256) {
      int r = c >> 3, s = c & 7;
      *(uint4*)&As[r][s * 8] = *(const uint4*)&A[(long)(row0 + r) * CDIM + kt + s * 8];
    }
    for (int c = tid; c < 512; c += 256) {
      int r = c >> 3, s = c & 7;
      *(uint4*)&Ws[r][s * 8] = *(const uint4*)&Wb[(long)(col0 + r) * CDIM + kt + s * 8];
    }
    __syncthreads();
#pragma unroll
    for (int s = 0; s < 2; ++s) {
      short8v a[4], bfr[2];
#pragma unroll
      for (int i = 0; i < 4; ++i)
        a[i] = *(const short8v*)&As[wm * 64 + i * 16 + l15][s * 32 + l16 * 8];
#pragma unroll
      for (int j = 0; j < 2; ++j)
        bfr[j] = *(const short8v*)&Ws[wn * 32 + j * 16 + l15][s * 32 + l16 * 8];
#pragma unroll
      for (int i = 0; i < 4; ++i)
#pragma unroll
        for (int j = 0; j < 2; ++j)
          acc[i][j] = __builtin_amdgcn_mfma_f32_16x16x32_bf16(a[i], bfr[j], acc[i][j], 0, 0, 0);
    }
  }
  const int btok = row0 >> 10;           // batch index (128 | 1024)
  const int ntok0 = row0 & 1023;
#pragma unroll
  for (int i = 0; i < 4; ++i)
#pragma unroll
    for (int j = 0; j < 2; ++j) {
      int col = col0 + wn * 32 + j * 16 + l15;
      int rbase = row0 + wm * 64 + i * 16 + l16 * 4;
#pragma unroll
      for (int r = 0; r < 4; ++r) {
        long o = (long)(rbase + r) * CDIM + col;
        if (flags == 0) ((ushort*)Cd)[o] = f2bf(acc[i][j][r]);
        else {
          int ntok = ntok0 + wm * 64 + i * 16 + l16 * 4 + r;
          float y = bf2f(ycr[((long)(btok * CDIM + col)) * 1024 + ntok]);
          ((float*)Cd)[o] = acc[i][j][r] + bias[col] + y;
        }
      }
    }
}

// fused q/k/v projection GEMMs (blockIdx.z selects)
__global__ __launch_bounds__(256) void gemm_qkv_k(
    const ushort* __restrict__ q0, const ushort* __restrict__ k0, const ushort* __restrict__ v0,
    const ushort* __restrict__ wqb, const ushort* __restrict__ wkb, const ushort* __restrict__ wvb,
    ushort* __restrict__ q1, ushort* __restrict__ k1, ushort* __restrict__ v1)
{
  const int z = blockIdx.z;
  const ushort* A  = z == 0 ? q0  : z == 1 ? k0  : v0;
  const ushort* Wb = z == 0 ? wqb : z == 1 ? wkb : wvb;
  ushort*       C  = z == 0 ? q1  : z == 1 ? k1  : v1;
  gemm_body(A, Wb, nullptr, nullptr, C, 0, blockIdx.x, blockIdx.y);
}

// final projection: out = A@wo^T + bo + x_fft (residual from yc)
__global__ __launch_bounds__(256) void gemm_out_k(
    const ushort* __restrict__ A, const ushort* __restrict__ Wb,
    const float* __restrict__ bias, const ushort* __restrict__ ycr,
    float* __restrict__ Cd)
{
  gemm_body(A, Wb, bias, ycr, Cd, 1, blockIdx.x, blockIdx.y);
}

// ---------------------------------------------------------------------------
// Kernel 3b: V transpose  v1 (b,n,h*48+d) -> vt ((b*8+h)*48+d, n)
// ---------------------------------------------------------------------------
__global__ __launch_bounds__(256) void vtrans_k(
    const ushort* __restrict__ v1, ushort* __restrict__ vt)
{
  const int bh = blockIdx.x, b = bh >> 3, h = bh & 7;
  const int n0 = blockIdx.y * 64;
  const int tid = threadIdx.x;
  __shared__ unsigned Lu[64][49];
  for (int i = tid; i < 384; i += 256) {
    int r = i / 6, s = i - r * 6;
    uint4 p = *(const uint4*)&v1[(long)(b * 1024 + n0 + r) * CDIM + h * 48 + s * 8];
    unsigned d0 = s * 8;
    Lu[r][d0 + 0] = p.x & 0xffffu;        Lu[r][d0 + 1] = p.x >> 16;
    Lu[r][d0 + 2] = p.y & 0xffffu;        Lu[r][d0 + 3] = p.y >> 16;
    Lu[r][d0 + 4] = p.z & 0xffffu;        Lu[r][d0 + 5] = p.z >> 16;
    Lu[r][d0 + 6] = p.w & 0xffffu;        Lu[r][d0 + 7] = p.w >> 16;
  }
  __syncthreads();
  for (int i = tid; i < 384; i += 256) {
    int d = i >> 3, s = i & 7;
    uint4 o;
    o.x = Lu[s * 8 + 0][d] | (Lu[s * 8 + 1][d] << 16);
    o.y = Lu[s * 8 + 2][d] | (Lu[s * 8 + 3][d] << 16);
    o.z = Lu[s * 8 + 4][d] | (Lu[s * 8 + 5][d] << 16);
    o.w = Lu[s * 8 + 6][d] | (Lu[s * 8 + 7][d] << 16);
    *(uint4*)&vt[((long)bh * 48 + d) * NPIX + n0 + s * 8] = o;
  }
}

// ---------------------------------------------------------------------------
// Kernel 4: MFMA flash attention (r10 structure + T14-lite reg prefetch).
// Single K/V LDS buffer, 2 barriers/iter, but the global loads for tile t+1
// are issued (into scalar regs) right after the staging barrier, so HBM
// latency hides under compute(t).  Swapped QK^T, cvt_pk P pack, no-max
// softmax, ones-MFMA row sums, Q direct from global.
// ---------------------------------------------------------------------------
__global__ __launch_bounds__(256) void attn_mfma_k(
    const ushort* __restrict__ q1, const ushort* __restrict__ k1,
    const ushort* __restrict__ vt, ushort* __restrict__ ao)
{
  const int bh = blockIdx.x, qt = blockIdx.y;
  const int b = bh >> 3, h = bh & 7;
  const int tid = threadIdx.x;
  const int w = tid >> 6, lane = tid & 63;
  const int l15 = lane & 15, l16 = lane >> 4;
  __shared__ ushort Ks[64][72], Vs[48][72], Ps[64][72];
  const float scale = 0.051031036307982884f;  // 384^-0.5
  const long base = (long)b * NPIX * CDIM + h * 48;
  const long vbase = (long)bh * 48 * NPIX;

  // per-thread staging descriptors (scalars -> no scratch).
  // chunk0: tid (<384, K); chunk1: tid+256 (mixed); chunk2: tid+512 (V)
  const int i0 = tid, i1 = tid + 256, i2 = tid + 512;
  const int r0 = i0 / 6, s0 = i0 - r0 * 6;
  const ushort* gp0 = k1 + base + (long)r0 * CDIM + s0 * 8;
  const long st0 = (long)64 * CDIM;
  ushort* lp0 = &Ks[r0][s0 * 8];
  const ushort* gp1; long st1; ushort* lp1;
  if (i1 < 384) {
    int r = i1 / 6, s = i1 - r * 6;
    gp1 = k1 + base + (long)r * CDIM + s * 8; st1 = (long)64 * CDIM; lp1 = &Ks[r][s * 8];
  } else {
    int j = i1 - 384, d = j >> 3, s = j & 7;
    gp1 = vt + vbase + (long)d * NPIX + s * 8; st1 = 64; lp1 = &Vs[d][s * 8];
  }
  const int j2 = i2 - 384, d2 = j2 >> 3, s2 = j2 & 7;
  const ushort* gp2 = vt + vbase + (long)d2 * NPIX + s2 * 8;
  const long st2 = 64;
  ushort* lp2 = &Vs[d2][s2 * 8];

  // zero K pad (cols 48..63), persists across iterations
  if (tid < 128) {
    uint4 z4 = {0u, 0u, 0u, 0u};
    int r = tid >> 1, s = tid & 1;
    *(uint4*)&Ks[r][48 + s * 8] = z4;
  }
  // Q fragments direct from global; d=48..63 lanes -> zero
  const long qrow = base + (long)(qt * 64 + w * 16 + l15) * CDIM;
  short8v qa0 = *(const short8v*)&q1[qrow + l16 * 8];
  short8v qa1;
  {
    short8v qz = {};
    short8v qv = *(const short8v*)&q1[qrow + ((l16 < 2) ? 32 + l16 * 8 : 0)];
    qa1 = (l16 < 2) ? qv : qz;
  }

  float lrun[4] = {0.f, 0.f, 0.f, 0.f};
  float4v accO[3];
#pragma unroll
  for (int fd = 0; fd < 3; ++fd) accO[fd] = (float4v){0.f, 0.f, 0.f, 0.f};
  short8v onesb;
#pragma unroll
  for (int j = 0; j < 8; ++j) onesb[j] = (short)0x3F80;  // bf16 1.0

  uint4 t0 = *(const uint4*)gp0;          // tile 0 loads
  uint4 t1 = *(const uint4*)gp1;
  uint4 t2 = *(const uint4*)gp2;

  for (int kt = 0; kt < 16; ++kt) {
    // write tile kt (LDS free: prev compute drained by end-of-iter barrier)
    *(uint4*)lp0 = t0;
    *(uint4*)lp1 = t1;
    *(uint4*)lp2 = t2;
    __syncthreads();
    if (kt + 1 < 16) {                    // issue loads for t+1 under compute
      t0 = *(const uint4*)(gp0 + (long)(kt + 1) * st0);
      t1 = *(const uint4*)(gp1 + (long)(kt + 1) * st1);
      t2 = *(const uint4*)(gp2 + (long)(kt + 1) * st2);
    }
    // swapped QK^T: S^T[k][q]; lane q = l15, k = fc*16 + l16*4 + r
    float4v sacc[4];
#pragma unroll
    for (int fc = 0; fc < 4; ++fc) {
      short8v kb0 = *(const short8v*)&Ks[fc * 16 + l15][l16 * 8];
      short8v kb1 = *(const short8v*)&Ks[fc * 16 + l15][32 + l16 * 8];
      sacc[fc] = (float4v){0.f, 0.f, 0.f, 0.f};
      sacc[fc] = __builtin_amdgcn_mfma_f32_16x16x32_bf16(kb0, qa0, sacc[fc], 0, 0, 0);
      sacc[fc] = __builtin_amdgcn_mfma_f32_16x16x32_bf16(kb1, qa1, sacc[fc], 0, 0, 0);
    }
    // P = exp(S*scale); pack pairs of consecutive k -> dword stores
    unsigned* prow = (unsigned*)&Ps[w * 16 + l15][0];
#pragma unroll
    for (int fc = 0; fc < 4; ++fc) {
      float p0 = __expf(sacc[fc][0] * scale);
      float p1 = __expf(sacc[fc][1] * scale);
      float p2 = __expf(sacc[fc][2] * scale);
      float p3 = __expf(sacc[fc][3] * scale);
      __hip_bfloat162 d01 = __float22bfloat162_rn(make_float2(p0, p1));
      __hip_bfloat162 d23 = __float22bfloat162_rn(make_float2(p2, p3));
      prow[fc * 8 + l16 * 2 + 0] = *(unsigned*)&d01;
      prow[fc * 8 + l16 * 2 + 1] = *(unsigned*)&d23;
    }
    // Ps is wave-private: intra-wave DS drain, no block barrier
    asm volatile("s_waitcnt lgkmcnt(0)" ::: "memory");
    __builtin_amdgcn_sched_barrier(0);
    short8v pa0 = *(const short8v*)&Ps[w * 16 + l15][l16 * 8];
    short8v pa1 = *(const short8v*)&Ps[w * 16 + l15][32 + l16 * 8];
    // row sums via ones-MFMA (matrix pipe, reuses pa fragments)
    float4v srow = (float4v){0.f, 0.f, 0.f, 0.f};
    srow = __builtin_amdgcn_mfma_f32_16x16x32_bf16(pa0, onesb, srow, 0, 0, 0);
    srow = __builtin_amdgcn_mfma_f32_16x16x32_bf16(pa1, onesb, srow, 0, 0, 0);
#pragma unroll
    for (int r = 0; r < 4; ++r) lrun[r] += srow[r];
    // PV: O(16x48) += P(16x64) . V(64x48)
#pragma unroll
    for (int fd = 0; fd < 3; ++fd) {
      short8v vb0 = *(const short8v*)&Vs[fd * 16 + l15][l16 * 8];
      short8v vb1 = *(const short8v*)&Vs[fd * 16 + l15][32 + l16 * 8];
      accO[fd] = __builtin_amdgcn_mfma_f32_16x16x32_bf16(pa0, vb0, accO[fd], 0, 0, 0);
      accO[fd] = __builtin_amdgcn_mfma_f32_16x16x32_bf16(pa1, vb1, accO[fd], 0, 0, 0);
    }
    __syncthreads();                      // compute done; LDS free for t+1
  }
  float inv[4];
#pragma unroll
  for (int r = 0; r < 4; ++r) inv[r] = 1.f / lrun[r];
#pragma unroll
  for (int fd = 0; fd < 3; ++fd)
#pragma unroll
    for (int r = 0; r < 4; ++r) {
      int qrow2 = qt * 64 + w * 16 + l16 * 4 + r;
      ao[base + (long)qrow2 * CDIM + fd * 16 + l15] = f2bf(accO[fd][r] * inv[r]);
    }
}

// ---------------------------------------------------------------------------
extern "C" void kernel_launch(void* const* d_in, const int* in_sizes, int n_in,
                              void* d_out, int out_size, void* d_ws, size_t ws_size,
                              hipStream_t stream) {
  const float* x   = (const float*)d_in[0];
  const float* cw  = (const float*)d_in[1];
  const float* dwq = (const float*)d_in[2];
  const float* dwk = (const float*)d_in[3];
  const float* dwv = (const float*)d_in[4];
  const float* gq  = (const float*)d_in[5];
  const float* bq  = (const float*)d_in[6];
  const float* mq  = (const float*)d_in[7];
  const float* vq  = (const float*)d_in[8];
  const float* gk  = (const float*)d_in[9];
  const float* bk  = (const float*)d_in[10];
  const float* mk  = (const float*)d_in[11];
  const float* vk  = (const float*)d_in[12];
  const float* gv  = (const float*)d_in[13];
  const float* bv  = (const float*)d_in[14];
  const float* mv  = (const float*)d_in[15];
  const float* vv  = (const float*)d_in[16];
  const float* wq  = (const float*)d_in[17];
  const float* wk  = (const float*)d_in[18];
  const float* wv  = (const float*)d_in[19];
  const float* wo  = (const float*)d_in[20];
  const float* bo  = (const float*)d_in[21];
  float* out = (float*)d_out;

  char* wsb = (char*)d_ws;
  const size_t H = (size_t)NB * NPIX * CDIM * 2;        // 6,291,456 B
  // slot plan (each H):
  // S0: xc -> q0 -> ao | S1: yc (until gemm_out) | S2: qc -> q1
  // S3: kc -> k1 | S4: vc -> v1 | S5: k0 | S6: v0 -> vtp | S7: weights+tbl
  ushort* xcp = (ushort*)(wsb + 0 * H);
  ushort* q0  = (ushort*)(wsb + 0 * H);
  ushort* ao  = (ushort*)(wsb + 0 * H);
  ushort* yc  = (ushort*)(wsb + 1 * H);
  ushort* qc  = (ushort*)(wsb + 2 * H);
  ushort* q1  = (ushort*)(wsb + 2 * H);
  ushort* kc  = (ushort*)(wsb + 3 * H);
  ushort* k1  = (ushort*)(wsb + 3 * H);
  ushort* vc  = (ushort*)(wsb + 4 * H);
  ushort* v1  = (ushort*)(wsb + 4 * H);
  ushort* k0  = (ushort*)(wsb + 5 * H);
  ushort* v0  = (ushort*)(wsb + 6 * H);
  ushort* vtp = (ushort*)(wsb + 6 * H);
  ushort* wqb = (ushort*)(wsb + 7 * H);
  ushort* wkb = wqb + CDIM * CDIM;
  ushort* wvb = wkb + CDIM * CDIM;
  ushort* wob = wvb + CDIM * CDIM;
  ushort* tbl = wob + CDIM * CDIM;                      // 5*1024 ushorts

  prep_k<<<dim3(164), 256, 0, stream>>>(tbl, wq, wk, wv, wo, wqb, wkb, wvb, wob);
  xtrans_k<<<dim3(NB, 12, 8), 256, 0, stream>>>(x, xcp);
  fft_conv_k<<<dim3(NB * CDIM), 256, 0, stream>>>(xcp, cw, tbl, dwq, dwk, dwv,
      gq, bq, mq, vq, gk, bk, mk, vk, gv, bv, mv, vv, yc, qc, kc, vc);
  trans_k<<<dim3(NB, 12, 8), 256, 0, stream>>>(qc, kc, vc, q0, k0, v0);
  // note: gemm z=0 writes q1 (S2) after trans_k consumed qc (S2) — ordered by stream
  gemm_qkv_k<<<dim3(64, 6, 3), 256, 0, stream>>>(q0, k0, v0, wqb, wkb, wvb, q1, k1, v1);
  vtrans_k<<<dim3(64, 16), 256, 0, stream>>>(v1, vtp);
  attn_mfma_k<<<dim3(64, 16), 256, 0, stream>>>(q1, k1, vtp, ao);
  gemm_out_k<<<dim3(64, 6), 256, 0, stream>>>(ao, wob, bo, yc, out);
}

// Round 12
// 132.776 us; speedup vs baseline: 1.2545x; 1.0587x over previous
//
#include <hip/hip_runtime.h>
#include <hip/hip_bf16.h>
#include <cmath>

#define CDIM 384
#define NB 8
#define NPIX 1024

typedef __attribute__((ext_vector_type(8))) short short8v;
typedef __attribute__((ext_vector_type(4))) float float4v;

__device__ __forceinline__ ushort f2bf(float f) {
  union { float f; unsigned u; } v; v.f = f;
  unsigned r = (v.u + 0x7fffu + ((v.u >> 16) & 1u)) >> 16;
  return (ushort)r;
}
__device__ __forceinline__ float bf2f(ushort u) {
  union { unsigned u; float f; } v; v.u = ((unsigned)u) << 16;
  return v.f;
}

// ---------------------------------------------------------------------------
// Kernel 0 (merged): blocks 0..19 bf16 twiddle tables; 20..163 projection
// weights -> bf16; 164..931 x (b,n,c) f32 -> xc (b,c,n) bf16 transpose.
// ---------------------------------------------------------------------------
__global__ __launch_bounds__(256) void prep_k(
    ushort* __restrict__ tbl,
    const float* __restrict__ wq, const float* __restrict__ wk,
    const float* __restrict__ wv, const float* __restrict__ wo,
    ushort* __restrict__ wqb, ushort* __restrict__ wkb,
    ushort* __restrict__ wvb, ushort* __restrict__ wob,
    const float* __restrict__ x, ushort* __restrict__ xc)
{
  __shared__ ushort T[128][33];
  if (blockIdx.x < 20) {
    int i = blockIdx.x * 256 + threadIdx.x;
    if (i >= 5 * 1024) return;
    int t = i >> 10, j = i & 1023, r = j >> 5, cidx = j & 31;
    float ang = (float)((r * cidx) & 31) * 0.19634954084936207f;
    float val;
    if (t == 0) val = cosf(ang);
    else if (t == 1) val = sinf(ang);
    else if (t == 2) val = -sinf(ang);
    else {
      if (cidx > 16) val = 0.f;
      else {
        float cv = (cidx == 0 || cidx == 16) ? 1.f : 2.f;
        val = (t == 3) ? cv * cosf(ang) : -cv * sinf(ang);
      }
    }
    tbl[i] = f2bf(val);
  } else if (blockIdx.x < 164) {
    int i = (blockIdx.x - 20) * 256 + threadIdx.x;
    if (i * 4 >= CDIM * CDIM) return;
    float4 va = *(const float4*)&wq[i * 4];
    float4 vb = *(const float4*)&wk[i * 4];
    float4 vc = *(const float4*)&wv[i * 4];
    float4 vd = *(const float4*)&wo[i * 4];
    ushort4 ra = { f2bf(va.x), f2bf(va.y), f2bf(va.z), f2bf(va.w) };
    ushort4 rb = { f2bf(vb.x), f2bf(vb.y), f2bf(vb.z), f2bf(vb.w) };
    ushort4 rc = { f2bf(vc.x), f2bf(vc.y), f2bf(vc.z), f2bf(vc.w) };
    ushort4 rd = { f2bf(vd.x), f2bf(vd.y), f2bf(vd.z), f2bf(vd.w) };
    *(ushort4*)&wqb[i * 4] = ra;
    *(ushort4*)&wkb[i * 4] = rb;
    *(ushort4*)&wvb[i * 4] = rc;
    *(ushort4*)&wob[i * 4] = rd;
  } else {
    int t = blockIdx.x - 164;             // 768 blocks: b*96 + (c0/32)*8 + n0/128
    int b = t / 96, rr = t % 96;
    int c0 = (rr >> 3) * 32, n0 = (rr & 7) * 128;
    for (int i = threadIdx.x; i < 4096; i += 256) {
      int n = i >> 5, c = i & 31;
      T[n][c] = f2bf(x[((long)(b * 1024 + n0 + n)) * CDIM + c0 + c]);
    }
    __syncthreads();
    for (int i = threadIdx.x; i < 4096; i += 256) {
      int c = i >> 7, n = i & 127;
      xc[((long)(b * CDIM + c0 + c)) * 1024 + n0 + n] = T[n][c];
    }
  }
}

// ---------------------------------------------------------------------------
// Kernel 1: spectral filter via MFMA + FUSED depthwise conv3x3 + BN.
// ---------------------------------------------------------------------------
__global__ __launch_bounds__(256) void fft_conv_k(
    const ushort* __restrict__ xc, const float* __restrict__ cw,
    const ushort* __restrict__ tbl,
    const float* __restrict__ dwq, const float* __restrict__ dwk, const float* __restrict__ dwv,
    const float* __restrict__ gq, const float* __restrict__ bq, const float* __restrict__ mq, const float* __restrict__ vq,
    const float* __restrict__ gk, const float* __restrict__ bk, const float* __restrict__ mk, const float* __restrict__ vk,
    const float* __restrict__ gv, const float* __restrict__ bv, const float* __restrict__ mv, const float* __restrict__ vv,
    ushort* __restrict__ yc,
    ushort* __restrict__ qc, ushort* __restrict__ kc, ushort* __restrict__ vc)
{
  const int b = blockIdx.x / CDIM, c = blockIdx.x % CDIM;
  const int tid = threadIdx.x;
  const int w = tid >> 6, lane = tid & 63;
  const int l15 = lane & 15, l16 = lane >> 4;
  __shared__ ushort B[11][32][40];
  __shared__ float Ysf[32][33];

  float wq9[9], wk9[9], wv9[9];
#pragma unroll
  for (int t = 0; t < 9; ++t) {
    wq9[t] = dwq[c * 9 + t];
    wk9[t] = dwk[c * 9 + t];
    wv9[t] = dwv[c * 9 + t];
  }
  float scq = gq[c] * rsqrtf(vq[c] + 1e-5f); float shq = bq[c] - mq[c] * scq;
  float sck = gk[c] * rsqrtf(vk[c] + 1e-5f); float shk = bk[c] - mk[c] * sck;
  float scv = gv[c] * rsqrtf(vv[c] + 1e-5f); float shv = bv[c] - mv[c] * scv;

  for (int i = tid; i < 640; i += 256) {                 // tables -> LDS
    int t = i >> 7, j = i & 127, r = j >> 2, s = j & 3;
    *(uint4*)&B[t][r][s * 8] = *(const uint4*)&tbl[t * 1024 + r * 32 + s * 8];
  }
  for (int i = tid; i < 1024; i += 256)                  // input -> Xt[w][h]
    B[5][i & 31][i >> 5] = xc[(long)(b * CDIM + c) * 1024 + i];
  __syncthreads();

  // stage1: R1[u,w] = sum_h Tc[u,h]*Xt[w,h];  I1 = sum_h Tsn[u,h]*Xt[w,h]
  for (int j = w; j < 8; j += 4) {
    int o = j & 1, ut = (j >> 1) & 1, wt = (j >> 2) & 1;
    short8v af = *(const short8v*)&B[o == 0 ? 0 : 2][ut * 16 + l15][l16 * 8];
    short8v bf = *(const short8v*)&B[5][wt * 16 + l15][l16 * 8];
    float4v acc = {0.f, 0.f, 0.f, 0.f};
    acc = __builtin_amdgcn_mfma_f32_16x16x32_bf16(af, bf, acc, 0, 0, 0);
    int dst = (o == 0) ? 7 : 8;
#pragma unroll
    for (int r = 0; r < 4; ++r)
      B[dst][ut * 16 + l16 * 4 + r][wt * 16 + l15] = f2bf(acc[r]);
  }
  __syncthreads();

  // stage2: Xfr[u,v] = R1.Tc + I1.Ts ; Xfi = I1.Tc + R1.Tsn  (fp32 raw store)
  for (int j = w; j < 8; j += 4) {
    int o = j & 1, ut = (j >> 1) & 1, vt = (j >> 2) & 1;
    short8v a1 = *(const short8v*)&B[o == 0 ? 7 : 8][ut * 16 + l15][l16 * 8];
    short8v b1 = *(const short8v*)&B[0][vt * 16 + l15][l16 * 8];
    short8v a2 = *(const short8v*)&B[o == 0 ? 8 : 7][ut * 16 + l15][l16 * 8];
    short8v b2 = *(const short8v*)&B[o == 0 ? 1 : 2][vt * 16 + l15][l16 * 8];
    float4v acc = {0.f, 0.f, 0.f, 0.f};
    acc = __builtin_amdgcn_mfma_f32_16x16x32_bf16(a1, b1, acc, 0, 0, 0);
    acc = __builtin_amdgcn_mfma_f32_16x16x32_bf16(a2, b2, acc, 0, 0, 0);
    int v = vt * 16 + l15;
    if (v < 17) {
      float* praw = (float*)&B[o == 0 ? 5 : 6][0][0];    // [32][20] f32 view
#pragma unroll
      for (int r = 0; r < 4; ++r)
        praw[(ut * 16 + l16 * 4 + r) * 20 + v] = acc[r];
    }
  }
  __syncthreads();

  // zero Ytr/Yti rows 17..31, then weight-multiply + transpose scatter
  for (int i = tid; i < 150; i += 256) {
    int buf = i / 75, j2 = i % 75, r2 = 17 + j2 / 5, s2 = j2 % 5;
    uint4 z = {0u, 0u, 0u, 0u};
    *(uint4*)&B[9 + buf][r2][s2 * 8] = z;
  }
  {
    const float* xfr = (const float*)&B[5][0][0];
    const float* xfi = (const float*)&B[6][0][0];
    for (int e = tid; e < 544; e += 256) {
      int u = e / 17, v = e - u * 17;
      float fr = xfr[u * 20 + v], fi = xfi[u * 20 + v];
      float2 wc = *(const float2*)&cw[((long)(c * 32 + u) * 17 + v) * 2];
      B[9][v][u]  = f2bf(fr * wc.x - fi * wc.y);
      B[10][v][u] = f2bf(fr * wc.y + fi * wc.x);
    }
  }
  __syncthreads();

  // stage3: Zr[h,v] = Tc(h).Ytr + Tsn(h).Yti ; Zi = Tc(h).Yti + Ts(h).Ytr
  for (int j = w; j < 8; j += 4) {
    int o = j & 1, ht = (j >> 1) & 1, vt = (j >> 2) & 1;
    short8v a1 = *(const short8v*)&B[0][ht * 16 + l15][l16 * 8];
    short8v b1 = *(const short8v*)&B[o == 0 ? 9 : 10][vt * 16 + l15][l16 * 8];
    short8v a2 = *(const short8v*)&B[o == 0 ? 2 : 1][ht * 16 + l15][l16 * 8];
    short8v b2 = *(const short8v*)&B[o == 0 ? 10 : 9][vt * 16 + l15][l16 * 8];
    float4v acc = {0.f, 0.f, 0.f, 0.f};
    acc = __builtin_amdgcn_mfma_f32_16x16x32_bf16(a1, b1, acc, 0, 0, 0);
    acc = __builtin_amdgcn_mfma_f32_16x16x32_bf16(a2, b2, acc, 0, 0, 0);
    int dst = (o == 0) ? 7 : 8;
#pragma unroll
    for (int r = 0; r < 4; ++r)
      B[dst][ht * 16 + l16 * 4 + r][vt * 16 + l15] = f2bf(acc[r]);
  }
  __syncthreads();

  // stage4: y[h,w] = (Zr.Uc^T + Zi.Us^T)/1024 -> Ysf (LDS) + yc (coalesced)
  {
    int ht = w & 1, wt = (w >> 1) & 1;
    short8v a1 = *(const short8v*)&B[7][ht * 16 + l15][l16 * 8];
    short8v b1 = *(const short8v*)&B[3][wt * 16 + l15][l16 * 8];
    short8v a2 = *(const short8v*)&B[8][ht * 16 + l15][l16 * 8];
    short8v b2 = *(const short8v*)&B[4][wt * 16 + l15][l16 * 8];
    float4v acc = {0.f, 0.f, 0.f, 0.f};
    acc = __builtin_amdgcn_mfma_f32_16x16x32_bf16(a1, b1, acc, 0, 0, 0);
    acc = __builtin_amdgcn_mfma_f32_16x16x32_bf16(a2, b2, acc, 0, 0, 0);
#pragma unroll
    for (int r = 0; r < 4; ++r) {
      int hh = ht * 16 + l16 * 4 + r, ww = wt * 16 + l15;
      float y = acc[r] * (1.0f / 1024.0f);
      Ysf[hh][ww] = y;
      yc[(long)(b * CDIM + c) * 1024 + hh * 32 + ww] = f2bf(y);
    }
  }
  __syncthreads();

  // fused depthwise 3x3 conv + BN -> qc/kc/vc (bf16, b,c,n — coalesced)
  for (int i = tid; i < 1024; i += 256) {
    int hh = i >> 5, ww = i & 31;
    float aq = 0.f, ak = 0.f, av = 0.f;
#pragma unroll
    for (int dy = 0; dy < 3; ++dy) {
      int y0 = hh + dy - 1;
#pragma unroll
      for (int dx = 0; dx < 3; ++dx) {
        int x0 = ww + dx - 1;
        float xv = (y0 >= 0 && y0 < 32 && x0 >= 0 && x0 < 32) ? Ysf[y0][x0] : 0.f;
        int t = dy * 3 + dx;
        aq += xv * wq9[t]; ak += xv * wk9[t]; av += xv * wv9[t];
      }
    }
    long o = (long)(b * CDIM + c) * 1024 + i;
    qc[o] = f2bf(aq * scq + shq);
    kc[o] = f2bf(ak * sck + shk);
    vc[o] = f2bf(av * scv + shv);
  }
}

// ---------------------------------------------------------------------------
// Kernel 1b: transpose (b,c,n)->(b,n,c) for qc/kc/vc -> q0/k0/v0 (bf16).
// ---------------------------------------------------------------------------
__global__ __launch_bounds__(256) void trans_k(
    const ushort* __restrict__ qc, const ushort* __restrict__ kc,
    const ushort* __restrict__ vc,
    ushort* __restrict__ q0, ushort* __restrict__ k0, ushort* __restrict__ v0)
{
  const int b = blockIdx.x, c0 = blockIdx.y * 32, n0 = blockIdx.z * 128;
  __shared__ ushort T[128][33];
  const ushort* srcs[3] = {qc, kc, vc};
#pragma unroll
  for (int p = 0; p < 3; ++p) {
    if (p) __syncthreads();
    const ushort* s = srcs[p];
    for (int i = threadIdx.x; i < 4096; i += 256) {
      int c = i >> 7, n = i & 127;
      T[n][c] = s[((long)(b * CDIM + c0 + c)) * 1024 + n0 + n];
    }
    __syncthreads();
    for (int i = threadIdx.x; i < 4096; i += 256) {
      int n = i >> 5, c = i & 31;
      long o = ((long)(b * 1024 + n0 + n)) * CDIM + c0 + c;
      ushort v = T[n][c];
      if (p == 0)      q0[o] = v;
      else if (p == 1) k0[o] = v;
      else             v0[o] = v;
    }
  }
}

// ---------------------------------------------------------------------------
// MFMA GEMM body  C[m,n'] = sum_k A[m,k] W[n',k]
// tile 128x64, BK=64, 4 waves (2x2), padded LDS (stride 72 bf16 = 144B).
// flags==0: bf16 store (n-major).  flags==1: fp32 write out = acc+bias+y
// (residual from ycr, (b,c,n) bf16).  flags==2: bf16 store TRANSPOSED
// (c-major: Cd[(b*CDIM+col)*1024 + ntok], packed ushort4).
// ---------------------------------------------------------------------------
__device__ __forceinline__ void gemm_body(
    const ushort* __restrict__ A, const ushort* __restrict__ Wb,
    const float* __restrict__ bias, const ushort* __restrict__ ycr,
    void* __restrict__ Cd, int flags, int bx, int by)
{
  __shared__ ushort As[128][72];
  __shared__ ushort Ws[64][72];
  const int tid = threadIdx.x;
  const int w = tid >> 6, lane = tid & 63;
  const int l15 = lane & 15, l16 = lane >> 4;
  const int wm = w >> 1, wn = w & 1;
  const int row0 = bx * 128, col0 = by * 64;
  float4v acc[4][2];
#pragma unroll
  for (int i = 0; i < 4; ++i)
#pragma unroll
    for (int j = 0; j < 2; ++j) acc[i][j] = (float4v){0.f, 0.f, 0.f, 0.f};
  for (int kt = 0; kt < CDIM; kt += 64) {
    if (kt) __syncthreads();
    for (int c = tid; c < 1024; c += 256) {
      int r = c >> 3, s = c & 7;
      *(uint4*)&As[r][s * 8] = *(const uint4*)&A[(long)(row0 + r) * CDIM + kt + s * 8];
    }
    for (int c = tid; c < 512; c += 256) {
      int r = c >> 3, s = c & 7;
      *(uint4*)&Ws[r][s * 8] = *(const uint4*)&Wb[(long)(col0 + r) * CDIM + kt + s * 8];
    }
    __syncthreads();
#pragma unroll
    for (int s = 0; s < 2; ++s) {
      short8v a[4], bfr[2];
#pragma unroll
      for (int i = 0; i < 4; ++i)
        a[i] = *(const short8v*)&As[wm * 64 + i * 16 + l15][s * 32 + l16 * 8];
#pragma unroll
      for (int j = 0; j < 2; ++j)
        bfr[j] = *(const short8v*)&Ws[wn * 32 + j * 16 + l15][s * 32 + l16 * 8];
#pragma unroll
      for (int i = 0; i < 4; ++i)
#pragma unroll
        for (int j = 0; j < 2; ++j)
          acc[i][j] = __builtin_amdgcn_mfma_f32_16x16x32_bf16(a[i], bfr[j], acc[i][j], 0, 0, 0);
    }
  }
  const int btok = row0 >> 10;           // batch index
  const int ntok0 = row0 & 1023;
#pragma unroll
  for (int i = 0; i < 4; ++i)
#pragma unroll
    for (int j = 0; j < 2; ++j) {
      int col = col0 + wn * 32 + j * 16 + l15;
      int rbase = row0 + wm * 64 + i * 16 + l16 * 4;
      int ntok = ntok0 + wm * 64 + i * 16 + l16 * 4;
      if (flags == 2) {
        ushort4 pk = { f2bf(acc[i][j][0]), f2bf(acc[i][j][1]),
                       f2bf(acc[i][j][2]), f2bf(acc[i][j][3]) };
        *(ushort4*)&((ushort*)Cd)[((long)(btok * CDIM + col)) * 1024 + ntok] = pk;
      } else if (flags == 1) {
        ushort4 yv = *(const ushort4*)&ycr[((long)(btok * CDIM + col)) * 1024 + ntok];
        float bcol = bias[col];
        float* op = (float*)Cd;
        op[(long)(rbase + 0) * CDIM + col] = acc[i][j][0] + bcol + bf2f(yv.x);
        op[(long)(rbase + 1) * CDIM + col] = acc[i][j][1] + bcol + bf2f(yv.y);
        op[(long)(rbase + 2) * CDIM + col] = acc[i][j][2] + bcol + bf2f(yv.z);
        op[(long)(rbase + 3) * CDIM + col] = acc[i][j][3] + bcol + bf2f(yv.w);
      } else {
#pragma unroll
        for (int r = 0; r < 4; ++r)
          ((ushort*)Cd)[(long)(rbase + r) * CDIM + col] = f2bf(acc[i][j][r]);
      }
    }
}

// fused q/k/v projection GEMMs (blockIdx.z selects).  z==2 (V) writes its
// output c-major (vtc) — replaces the old vtrans kernel.
__global__ __launch_bounds__(256) void gemm_qkv_k(
    const ushort* __restrict__ q0, const ushort* __restrict__ k0, const ushort* __restrict__ v0,
    const ushort* __restrict__ wqb, const ushort* __restrict__ wkb, const ushort* __restrict__ wvb,
    ushort* __restrict__ q1, ushort* __restrict__ k1, ushort* __restrict__ vtc)
{
  const int z = blockIdx.z;
  const ushort* A  = z == 0 ? q0  : z == 1 ? k0  : v0;
  const ushort* Wb = z == 0 ? wqb : z == 1 ? wkb : wvb;
  ushort*       C  = z == 0 ? q1  : z == 1 ? k1  : vtc;
  gemm_body(A, Wb, nullptr, nullptr, C, z == 2 ? 2 : 0, blockIdx.x, blockIdx.y);
}

// final projection: out = A@wo^T + bo + x_fft (residual from yc)
__global__ __launch_bounds__(256) void gemm_out_k(
    const ushort* __restrict__ A, const ushort* __restrict__ Wb,
    const float* __restrict__ bias, const ushort* __restrict__ ycr,
    float* __restrict__ Cd)
{
  gemm_body(A, Wb, bias, ycr, Cd, 1, blockIdx.x, blockIdx.y);
}

// ---------------------------------------------------------------------------
// Kernel 4: MFMA flash attention (r10 structure + T14-lite reg prefetch).
// Swapped QK^T, cvt_pk P pack, no-max softmax, ones-MFMA row sums, Q direct
// from global, single K/V LDS buffer with next-tile loads issued under
// compute.  V comes from vtc (c-major GEMM output, same layout as old vt).
// ---------------------------------------------------------------------------
__global__ __launch_bounds__(256) void attn_mfma_k(
    const ushort* __restrict__ q1, const ushort* __restrict__ k1,
    const ushort* __restrict__ vt, ushort* __restrict__ ao)
{
  const int bh = blockIdx.x, qt = blockIdx.y;
  const int b = bh >> 3, h = bh & 7;
  const int tid = threadIdx.x;
  const int w = tid >> 6, lane = tid & 63;
  const int l15 = lane & 15, l16 = lane >> 4;
  __shared__ ushort Ks[64][72], Vs[48][72], Ps[64][72];
  const float scale = 0.051031036307982884f;  // 384^-0.5
  const long base = (long)b * NPIX * CDIM + h * 48;
  const long vbase = (long)bh * 48 * NPIX;

  // per-thread staging descriptors (scalars -> no scratch).
  const int i0 = tid, i1 = tid + 256, i2 = tid + 512;
  const int r0 = i0 / 6, s0 = i0 - r0 * 6;
  const ushort* gp0 = k1 + base + (long)r0 * CDIM + s0 * 8;
  const long st0 = (long)64 * CDIM;
  ushort* lp0 = &Ks[r0][s0 * 8];
  const ushort* gp1; long st1; ushort* lp1;
  if (i1 < 384) {
    int r = i1 / 6, s = i1 - r * 6;
    gp1 = k1 + base + (long)r * CDIM + s * 8; st1 = (long)64 * CDIM; lp1 = &Ks[r][s * 8];
  } else {
    int j = i1 - 384, d = j >> 3, s = j & 7;
    gp1 = vt + vbase + (long)d * NPIX + s * 8; st1 = 64; lp1 = &Vs[d][s * 8];
  }
  const int j2 = i2 - 384, d2 = j2 >> 3, s2 = j2 & 7;
  const ushort* gp2 = vt + vbase + (long)d2 * NPIX + s2 * 8;
  const long st2 = 64;
  ushort* lp2 = &Vs[d2][s2 * 8];

  // zero K pad (cols 48..63), persists across iterations
  if (tid < 128) {
    uint4 z4 = {0u, 0u, 0u, 0u};
    int r = tid >> 1, s = tid & 1;
    *(uint4*)&Ks[r][48 + s * 8] = z4;
  }
  // Q fragments direct from global; d=48..63 lanes -> zero
  const long qrow = base + (long)(qt * 64 + w * 16 + l15) * CDIM;
  short8v qa0 = *(const short8v*)&q1[qrow + l16 * 8];
  short8v qa1;
  {
    short8v qz = {};
    short8v qv = *(const short8v*)&q1[qrow + ((l16 < 2) ? 32 + l16 * 8 : 0)];
    qa1 = (l16 < 2) ? qv : qz;
  }

  float lrun[4] = {0.f, 0.f, 0.f, 0.f};
  float4v accO[3];
#pragma unroll
  for (int fd = 0; fd < 3; ++fd) accO[fd] = (float4v){0.f, 0.f, 0.f, 0.f};
  short8v onesb;
#pragma unroll
  for (int j = 0; j < 8; ++j) onesb[j] = (short)0x3F80;  // bf16 1.0

  uint4 t0 = *(const uint4*)gp0;          // tile 0 loads
  uint4 t1 = *(const uint4*)gp1;
  uint4 t2 = *(const uint4*)gp2;

  for (int kt = 0; kt < 16; ++kt) {
    *(uint4*)lp0 = t0;
    *(uint4*)lp1 = t1;
    *(uint4*)lp2 = t2;
    __syncthreads();
    if (kt + 1 < 16) {                    // issue loads for t+1 under compute
      t0 = *(const uint4*)(gp0 + (long)(kt + 1) * st0);
      t1 = *(const uint4*)(gp1 + (long)(kt + 1) * st1);
      t2 = *(const uint4*)(gp2 + (long)(kt + 1) * st2);
    }
    // swapped QK^T: S^T[k][q]; lane q = l15, k = fc*16 + l16*4 + r
    float4v sacc[4];
#pragma unroll
    for (int fc = 0; fc < 4; ++fc) {
      short8v kb0 = *(const short8v*)&Ks[fc * 16 + l15][l16 * 8];
      short8v kb1 = *(const short8v*)&Ks[fc * 16 + l15][32 + l16 * 8];
      sacc[fc] = (float4v){0.f, 0.f, 0.f, 0.f};
      sacc[fc] = __builtin_amdgcn_mfma_f32_16x16x32_bf16(kb0, qa0, sacc[fc], 0, 0, 0);
      sacc[fc] = __builtin_amdgcn_mfma_f32_16x16x32_bf16(kb1, qa1, sacc[fc], 0, 0, 0);
    }
    // P = exp(S*scale); pack pairs of consecutive k -> dword stores
    unsigned* prow = (unsigned*)&Ps[w * 16 + l15][0];
#pragma unroll
    for (int fc = 0; fc < 4; ++fc) {
      float p0 = __expf(sacc[fc][0] * scale);
      float p1 = __expf(sacc[fc][1] * scale);
      float p2 = __expf(sacc[fc][2] * scale);
      float p3 = __expf(sacc[fc][3] * scale);
      __hip_bfloat162 d01 = __float22bfloat162_rn(make_float2(p0, p1));
      __hip_bfloat162 d23 = __float22bfloat162_rn(make_float2(p2, p3));
      prow[fc * 8 + l16 * 2 + 0] = *(unsigned*)&d01;
      prow[fc * 8 + l16 * 2 + 1] = *(unsigned*)&d23;
    }
    // Ps is wave-private: intra-wave DS drain, no block barrier
    asm volatile("s_waitcnt lgkmcnt(0)" ::: "memory");
    __builtin_amdgcn_sched_barrier(0);
    short8v pa0 = *(const short8v*)&Ps[w * 16 + l15][l16 * 8];
    short8v pa1 = *(const short8v*)&Ps[w * 16 + l15][32 + l16 * 8];
    // row sums via ones-MFMA (matrix pipe, reuses pa fragments)
    float4v srow = (float4v){0.f, 0.f, 0.f, 0.f};
    srow = __builtin_amdgcn_mfma_f32_16x16x32_bf16(pa0, onesb, srow, 0, 0, 0);
    srow = __builtin_amdgcn_mfma_f32_16x16x32_bf16(pa1, onesb, srow, 0, 0, 0);
#pragma unroll
    for (int r = 0; r < 4; ++r) lrun[r] += srow[r];
    // PV: O(16x48) += P(16x64) . V(64x48)
#pragma unroll
    for (int fd = 0; fd < 3; ++fd) {
      short8v vb0 = *(const short8v*)&Vs[fd * 16 + l15][l16 * 8];
      short8v vb1 = *(const short8v*)&Vs[fd * 16 + l15][32 + l16 * 8];
      accO[fd] = __builtin_amdgcn_mfma_f32_16x16x32_bf16(pa0, vb0, accO[fd], 0, 0, 0);
      accO[fd] = __builtin_amdgcn_mfma_f32_16x16x32_bf16(pa1, vb1, accO[fd], 0, 0, 0);
    }
    __syncthreads();                      // compute done; LDS free for t+1
  }
  float inv[4];
#pragma unroll
  for (int r = 0; r < 4; ++r) inv[r] = 1.f / lrun[r];
#pragma unroll
  for (int fd = 0; fd < 3; ++fd)
#pragma unroll
    for (int r = 0; r < 4; ++r) {
      int qrow2 = qt * 64 + w * 16 + l16 * 4 + r;
      ao[base + (long)qrow2 * CDIM + fd * 16 + l15] = f2bf(accO[fd][r] * inv[r]);
    }
}

// ---------------------------------------------------------------------------
extern "C" void kernel_launch(void* const* d_in, const int* in_sizes, int n_in,
                              void* d_out, int out_size, void* d_ws, size_t ws_size,
                              hipStream_t stream) {
  const float* x   = (const float*)d_in[0];
  const float* cw  = (const float*)d_in[1];
  const float* dwq = (const float*)d_in[2];
  const float* dwk = (const float*)d_in[3];
  const float* dwv = (const float*)d_in[4];
  const float* gq  = (const float*)d_in[5];
  const float* bq  = (const float*)d_in[6];
  const float* mq  = (const float*)d_in[7];
  const float* vq  = (const float*)d_in[8];
  const float* gk  = (const float*)d_in[9];
  const float* bk  = (const float*)d_in[10];
  const float* mk  = (const float*)d_in[11];
  const float* vk  = (const float*)d_in[12];
  const float* gv  = (const float*)d_in[13];
  const float* bv  = (const float*)d_in[14];
  const float* mv  = (const float*)d_in[15];
  const float* vv  = (const float*)d_in[16];
  const float* wq  = (const float*)d_in[17];
  const float* wk  = (const float*)d_in[18];
  const float* wv  = (const float*)d_in[19];
  const float* wo  = (const float*)d_in[20];
  const float* bo  = (const float*)d_in[21];
  float* out = (float*)d_out;

  char* wsb = (char*)d_ws;
  const size_t H = (size_t)NB * NPIX * CDIM * 2;        // 6,291,456 B
  // slot plan (each H):
  // S0: xc -> q0 -> ao | S1: yc (until gemm_out) | S2: qc -> q1
  // S3: kc -> k1 | S4: vc -> vtc | S5: k0 | S6: v0 | S7: weights+tbl
  ushort* xcp = (ushort*)(wsb + 0 * H);
  ushort* q0  = (ushort*)(wsb + 0 * H);
  ushort* ao  = (ushort*)(wsb + 0 * H);
  ushort* yc  = (ushort*)(wsb + 1 * H);
  ushort* qc  = (ushort*)(wsb + 2 * H);
  ushort* q1  = (ushort*)(wsb + 2 * H);
  ushort* kc  = (ushort*)(wsb + 3 * H);
  ushort* k1  = (ushort*)(wsb + 3 * H);
  ushort* vc  = (ushort*)(wsb + 4 * H);
  ushort* vtc = (ushort*)(wsb + 4 * H);
  ushort* k0  = (ushort*)(wsb + 5 * H);
  ushort* v0  = (ushort*)(wsb + 6 * H);
  ushort* wqb = (ushort*)(wsb + 7 * H);
  ushort* wkb = wqb + CDIM * CDIM;
  ushort* wvb = wkb + CDIM * CDIM;
  ushort* wob = wvb + CDIM * CDIM;
  ushort* tbl = wob + CDIM * CDIM;                      // 5*1024 ushorts

  prep_k<<<dim3(932), 256, 0, stream>>>(tbl, wq, wk, wv, wo,
      wqb, wkb, wvb, wob, x, xcp);
  fft_conv_k<<<dim3(NB * CDIM), 256, 0, stream>>>(xcp, cw, tbl, dwq, dwk, dwv,
      gq, bq, mq, vq, gk, bk, mk, vk, gv, bv, mv, vv, yc, qc, kc, vc);
  trans_k<<<dim3(NB, 12, 8), 256, 0, stream>>>(qc, kc, vc, q0, k0, v0);
  // gemm z=0 writes q1 (S2, qc dead); z=2 writes vtc (S4, vc dead) c-major
  gemm_qkv_k<<<dim3(64, 6, 3), 256, 0, stream>>>(q0, k0, v0, wqb, wkb, wvb, q1, k1, vtc);
  attn_mfma_k<<<dim3(64, 16), 256, 0, stream>>>(q1, k1, vtc, ao);
  gemm_out_k<<<dim3(64, 6), 256, 0, stream>>>(ao, wob, bo, yc, out);
}

// Round 13
// 103.268 us; speedup vs baseline: 1.6129x; 1.2857x over previous
//
#include <hip/hip_runtime.h>
#include <hip/hip_bf16.h>
#include <cmath>

#define CDIM 384
#define NB 8
#define NPIX 1024

typedef __attribute__((ext_vector_type(8))) short short8v;
typedef __attribute__((ext_vector_type(4))) float float4v;

__device__ __forceinline__ ushort f2bf(float f) {
  union { float f; unsigned u; } v; v.f = f;
  unsigned r = (v.u + 0x7fffu + ((v.u >> 16) & 1u)) >> 16;
  return (ushort)r;
}
__device__ __forceinline__ float bf2f(ushort u) {
  union { unsigned u; float f; } v; v.u = ((unsigned)u) << 16;
  return v.f;
}

// ---------------------------------------------------------------------------
// Kernel 0 (merged): blocks 0..19 bf16 twiddle tables; 20..163 projection
// weights -> bf16; 164..931 x (b,n,c) f32 -> xc (b,c,n) bf16 transpose.
// ---------------------------------------------------------------------------
__global__ __launch_bounds__(256) void prep_k(
    ushort* __restrict__ tbl,
    const float* __restrict__ wq, const float* __restrict__ wk,
    const float* __restrict__ wv, const float* __restrict__ wo,
    ushort* __restrict__ wqb, ushort* __restrict__ wkb,
    ushort* __restrict__ wvb, ushort* __restrict__ wob,
    const float* __restrict__ x, ushort* __restrict__ xc)
{
  __shared__ ushort T[128][33];
  if (blockIdx.x < 20) {
    int i = blockIdx.x * 256 + threadIdx.x;
    if (i >= 5 * 1024) return;
    int t = i >> 10, j = i & 1023, r = j >> 5, cidx = j & 31;
    float ang = (float)((r * cidx) & 31) * 0.19634954084936207f;
    float val;
    if (t == 0) val = cosf(ang);
    else if (t == 1) val = sinf(ang);
    else if (t == 2) val = -sinf(ang);
    else {
      if (cidx > 16) val = 0.f;
      else {
        float cv = (cidx == 0 || cidx == 16) ? 1.f : 2.f;
        val = (t == 3) ? cv * cosf(ang) : -cv * sinf(ang);
      }
    }
    tbl[i] = f2bf(val);
  } else if (blockIdx.x < 164) {
    int i = (blockIdx.x - 20) * 256 + threadIdx.x;
    if (i * 4 >= CDIM * CDIM) return;
    float4 va = *(const float4*)&wq[i * 4];
    float4 vb = *(const float4*)&wk[i * 4];
    float4 vc = *(const float4*)&wv[i * 4];
    float4 vd = *(const float4*)&wo[i * 4];
    ushort4 ra = { f2bf(va.x), f2bf(va.y), f2bf(va.z), f2bf(va.w) };
    ushort4 rb = { f2bf(vb.x), f2bf(vb.y), f2bf(vb.z), f2bf(vb.w) };
    ushort4 rc = { f2bf(vc.x), f2bf(vc.y), f2bf(vc.z), f2bf(vc.w) };
    ushort4 rd = { f2bf(vd.x), f2bf(vd.y), f2bf(vd.z), f2bf(vd.w) };
    *(ushort4*)&wqb[i * 4] = ra;
    *(ushort4*)&wkb[i * 4] = rb;
    *(ushort4*)&wvb[i * 4] = rc;
    *(ushort4*)&wob[i * 4] = rd;
  } else {
    int t = blockIdx.x - 164;             // 768 blocks: b*96 + (c0/32)*8 + n0/128
    int b = t / 96, rr = t % 96;
    int c0 = (rr >> 3) * 32, n0 = (rr & 7) * 128;
    for (int i = threadIdx.x; i < 4096; i += 256) {
      int n = i >> 5, c = i & 31;
      T[n][c] = f2bf(x[((long)(b * 1024 + n0 + n)) * CDIM + c0 + c]);
    }
    __syncthreads();
    for (int i = threadIdx.x; i < 4096; i += 256) {
      int c = i >> 7, n = i & 127;
      xc[((long)(b * CDIM + c0 + c)) * 1024 + n0 + n] = T[n][c];
    }
  }
}

// ---------------------------------------------------------------------------
// Kernel 1: spectral filter via MFMA + FUSED depthwise conv3x3 + BN.
// ---------------------------------------------------------------------------
__global__ __launch_bounds__(256) void fft_conv_k(
    const ushort* __restrict__ xc, const float* __restrict__ cw,
    const ushort* __restrict__ tbl,
    const float* __restrict__ dwq, const float* __restrict__ dwk, const float* __restrict__ dwv,
    const float* __restrict__ gq, const float* __restrict__ bq, const float* __restrict__ mq, const float* __restrict__ vq,
    const float* __restrict__ gk, const float* __restrict__ bk, const float* __restrict__ mk, const float* __restrict__ vk,
    const float* __restrict__ gv, const float* __restrict__ bv, const float* __restrict__ mv, const float* __restrict__ vv,
    ushort* __restrict__ yc,
    ushort* __restrict__ qc, ushort* __restrict__ kc, ushort* __restrict__ vc)
{
  const int b = blockIdx.x / CDIM, c = blockIdx.x % CDIM;
  const int tid = threadIdx.x;
  const int w = tid >> 6, lane = tid & 63;
  const int l15 = lane & 15, l16 = lane >> 4;
  __shared__ ushort B[11][32][40];
  __shared__ float Ysf[32][33];

  float wq9[9], wk9[9], wv9[9];
#pragma unroll
  for (int t = 0; t < 9; ++t) {
    wq9[t] = dwq[c * 9 + t];
    wk9[t] = dwk[c * 9 + t];
    wv9[t] = dwv[c * 9 + t];
  }
  float scq = gq[c] * rsqrtf(vq[c] + 1e-5f); float shq = bq[c] - mq[c] * scq;
  float sck = gk[c] * rsqrtf(vk[c] + 1e-5f); float shk = bk[c] - mk[c] * sck;
  float scv = gv[c] * rsqrtf(vv[c] + 1e-5f); float shv = bv[c] - mv[c] * scv;

  for (int i = tid; i < 640; i += 256) {                 // tables -> LDS
    int t = i >> 7, j = i & 127, r = j >> 2, s = j & 3;
    *(uint4*)&B[t][r][s * 8] = *(const uint4*)&tbl[t * 1024 + r * 32 + s * 8];
  }
  for (int i = tid; i < 1024; i += 256)                  // input -> Xt[w][h]
    B[5][i & 31][i >> 5] = xc[(long)(b * CDIM + c) * 1024 + i];
  __syncthreads();

  // stage1: R1[u,w] = sum_h Tc[u,h]*Xt[w,h];  I1 = sum_h Tsn[u,h]*Xt[w,h]
  for (int j = w; j < 8; j += 4) {
    int o = j & 1, ut = (j >> 1) & 1, wt = (j >> 2) & 1;
    short8v af = *(const short8v*)&B[o == 0 ? 0 : 2][ut * 16 + l15][l16 * 8];
    short8v bf = *(const short8v*)&B[5][wt * 16 + l15][l16 * 8];
    float4v acc = {0.f, 0.f, 0.f, 0.f};
    acc = __builtin_amdgcn_mfma_f32_16x16x32_bf16(af, bf, acc, 0, 0, 0);
    int dst = (o == 0) ? 7 : 8;
#pragma unroll
    for (int r = 0; r < 4; ++r)
      B[dst][ut * 16 + l16 * 4 + r][wt * 16 + l15] = f2bf(acc[r]);
  }
  __syncthreads();

  // stage2: Xfr[u,v] = R1.Tc + I1.Ts ; Xfi = I1.Tc + R1.Tsn  (fp32 raw store)
  for (int j = w; j < 8; j += 4) {
    int o = j & 1, ut = (j >> 1) & 1, vt = (j >> 2) & 1;
    short8v a1 = *(const short8v*)&B[o == 0 ? 7 : 8][ut * 16 + l15][l16 * 8];
    short8v b1 = *(const short8v*)&B[0][vt * 16 + l15][l16 * 8];
    short8v a2 = *(const short8v*)&B[o == 0 ? 8 : 7][ut * 16 + l15][l16 * 8];
    short8v b2 = *(const short8v*)&B[o == 0 ? 1 : 2][vt * 16 + l15][l16 * 8];
    float4v acc = {0.f, 0.f, 0.f, 0.f};
    acc = __builtin_amdgcn_mfma_f32_16x16x32_bf16(a1, b1, acc, 0, 0, 0);
    acc = __builtin_amdgcn_mfma_f32_16x16x32_bf16(a2, b2, acc, 0, 0, 0);
    int v = vt * 16 + l15;
    if (v < 17) {
      float* praw = (float*)&B[o == 0 ? 5 : 6][0][0];    // [32][20] f32 view
#pragma unroll
      for (int r = 0; r < 4; ++r)
        praw[(ut * 16 + l16 * 4 + r) * 20 + v] = acc[r];
    }
  }
  __syncthreads();

  // zero Ytr/Yti rows 17..31, then weight-multiply + transpose scatter
  for (int i = tid; i < 150; i += 256) {
    int buf = i / 75, j2 = i % 75, r2 = 17 + j2 / 5, s2 = j2 % 5;
    uint4 z = {0u, 0u, 0u, 0u};
    *(uint4*)&B[9 + buf][r2][s2 * 8] = z;
  }
  {
    const float* xfr = (const float*)&B[5][0][0];
    const float* xfi = (const float*)&B[6][0][0];
    for (int e = tid; e < 544; e += 256) {
      int u = e / 17, v = e - u * 17;
      float fr = xfr[u * 20 + v], fi = xfi[u * 20 + v];
      float2 wc = *(const float2*)&cw[((long)(c * 32 + u) * 17 + v) * 2];
      B[9][v][u]  = f2bf(fr * wc.x - fi * wc.y);
      B[10][v][u] = f2bf(fr * wc.y + fi * wc.x);
    }
  }
  __syncthreads();

  // stage3: Zr[h,v] = Tc(h).Ytr + Tsn(h).Yti ; Zi = Tc(h).Yti + Ts(h).Ytr
  for (int j = w; j < 8; j += 4) {
    int o = j & 1, ht = (j >> 1) & 1, vt = (j >> 2) & 1;
    short8v a1 = *(const short8v*)&B[0][ht * 16 + l15][l16 * 8];
    short8v b1 = *(const short8v*)&B[o == 0 ? 9 : 10][vt * 16 + l15][l16 * 8];
    short8v a2 = *(const short8v*)&B[o == 0 ? 2 : 1][ht * 16 + l15][l16 * 8];
    short8v b2 = *(const short8v*)&B[o == 0 ? 10 : 9][vt * 16 + l15][l16 * 8];
    float4v acc = {0.f, 0.f, 0.f, 0.f};
    acc = __builtin_amdgcn_mfma_f32_16x16x32_bf16(a1, b1, acc, 0, 0, 0);
    acc = __builtin_amdgcn_mfma_f32_16x16x32_bf16(a2, b2, acc, 0, 0, 0);
    int dst = (o == 0) ? 7 : 8;
#pragma unroll
    for (int r = 0; r < 4; ++r)
      B[dst][ht * 16 + l16 * 4 + r][vt * 16 + l15] = f2bf(acc[r]);
  }
  __syncthreads();

  // stage4: y[h,w] = (Zr.Uc^T + Zi.Us^T)/1024 -> Ysf (LDS) + yc (coalesced)
  {
    int ht = w & 1, wt = (w >> 1) & 1;
    short8v a1 = *(const short8v*)&B[7][ht * 16 + l15][l16 * 8];
    short8v b1 = *(const short8v*)&B[3][wt * 16 + l15][l16 * 8];
    short8v a2 = *(const short8v*)&B[8][ht * 16 + l15][l16 * 8];
    short8v b2 = *(const short8v*)&B[4][wt * 16 + l15][l16 * 8];
    float4v acc = {0.f, 0.f, 0.f, 0.f};
    acc = __builtin_amdgcn_mfma_f32_16x16x32_bf16(a1, b1, acc, 0, 0, 0);
    acc = __builtin_amdgcn_mfma_f32_16x16x32_bf16(a2, b2, acc, 0, 0, 0);
#pragma unroll
    for (int r = 0; r < 4; ++r) {
      int hh = ht * 16 + l16 * 4 + r, ww = wt * 16 + l15;
      float y = acc[r] * (1.0f / 1024.0f);
      Ysf[hh][ww] = y;
      yc[(long)(b * CDIM + c) * 1024 + hh * 32 + ww] = f2bf(y);
    }
  }
  __syncthreads();

  // fused depthwise 3x3 conv + BN -> qc/kc/vc (bf16, b,c,n — coalesced)
  for (int i = tid; i < 1024; i += 256) {
    int hh = i >> 5, ww = i & 31;
    float aq = 0.f, ak = 0.f, av = 0.f;
#pragma unroll
    for (int dy = 0; dy < 3; ++dy) {
      int y0 = hh + dy - 1;
#pragma unroll
      for (int dx = 0; dx < 3; ++dx) {
        int x0 = ww + dx - 1;
        float xv = (y0 >= 0 && y0 < 32 && x0 >= 0 && x0 < 32) ? Ysf[y0][x0] : 0.f;
        int t = dy * 3 + dx;
        aq += xv * wq9[t]; ak += xv * wk9[t]; av += xv * wv9[t];
      }
    }
    long o = (long)(b * CDIM + c) * 1024 + i;
    qc[o] = f2bf(aq * scq + shq);
    kc[o] = f2bf(ak * sck + shk);
    vc[o] = f2bf(av * scv + shv);
  }
}

// ---------------------------------------------------------------------------
// MFMA GEMM body  C[m,n'] = sum_k A[m,k] W[n',k]
// tile 128x64, BK=64, 4 waves (2x2), padded LDS (stride 72 bf16 = 144B).
// CMA=true: A is c-major (b,c,n); staging does the n<->c transpose in LDS
//   with a row-XOR column swizzle (col ^ (row&56)) to kill bank conflicts.
// flags==0: bf16 store (n-major).  flags==1: fp32 write out = acc+bias+y
// (residual from ycr, c-major bf16).  flags==2: bf16 store c-major (ushort4).
// ---------------------------------------------------------------------------
template<bool CMA>
__device__ __forceinline__ void gemm_body(
    const ushort* __restrict__ A, const ushort* __restrict__ Wb,
    const float* __restrict__ bias, const ushort* __restrict__ ycr,
    void* __restrict__ Cd, int flags, int bx, int by)
{
  __shared__ ushort As[128][72];
  __shared__ ushort Ws[64][72];
  const int tid = threadIdx.x;
  const int w = tid >> 6, lane = tid & 63;
  const int l15 = lane & 15, l16 = lane >> 4;
  const int wm = w >> 1, wn = w & 1;
  const int row0 = bx * 128, col0 = by * 64;
  const int btok = row0 >> 10;           // batch index
  const int ntok0 = row0 & 1023;
  float4v acc[4][2];
#pragma unroll
  for (int i = 0; i < 4; ++i)
#pragma unroll
    for (int j = 0; j < 2; ++j) acc[i][j] = (float4v){0.f, 0.f, 0.f, 0.f};
  for (int kt = 0; kt < CDIM; kt += 64) {
    if (kt) __syncthreads();
    if (CMA) {
      // A c-major: thread (g=tid&15, u=tid>>4) loads 4 channels x 8 tokens,
      // register-transposes, writes 8 uint2 at swizzled columns.
      const int g = tid & 15, u = tid >> 4;
      const int c0 = u * 4;
      const long abase = ((long)(btok * CDIM + kt + c0)) * 1024 + ntok0 + g * 8;
      uint4 t0 = *(const uint4*)&A[abase + 0 * 1024];
      uint4 t1 = *(const uint4*)&A[abase + 1 * 1024];
      uint4 t2 = *(const uint4*)&A[abase + 2 * 1024];
      uint4 t3 = *(const uint4*)&A[abase + 3 * 1024];
      const ushort* s0 = (const ushort*)&t0;
      const ushort* s1 = (const ushort*)&t1;
      const ushort* s2 = (const ushort*)&t2;
      const ushort* s3 = (const ushort*)&t3;
      const int colu = c0 ^ ((g & 7) << 3);
#pragma unroll
      for (int i = 0; i < 8; ++i) {
        uint2 wv;
        wv.x = (unsigned)s0[i] | ((unsigned)s1[i] << 16);
        wv.y = (unsigned)s2[i] | ((unsigned)s3[i] << 16);
        *(uint2*)&As[g * 8 + i][colu] = wv;
      }
    } else {
      for (int c = tid; c < 1024; c += 256) {
        int r = c >> 3, s = c & 7;
        *(uint4*)&As[r][s * 8] = *(const uint4*)&A[(long)(row0 + r) * CDIM + kt + s * 8];
      }
    }
    for (int c = tid; c < 512; c += 256) {
      int r = c >> 3, s = c & 7;
      *(uint4*)&Ws[r][s * 8] = *(const uint4*)&Wb[(long)(col0 + r) * CDIM + kt + s * 8];
    }
    __syncthreads();
#pragma unroll
    for (int s = 0; s < 2; ++s) {
      short8v a[4], bfr[2];
#pragma unroll
      for (int i = 0; i < 4; ++i) {
        int arow = wm * 64 + i * 16 + l15;
        int acol = s * 32 + l16 * 8;
        if (CMA) acol ^= (arow & 56);
        a[i] = *(const short8v*)&As[arow][acol];
      }
#pragma unroll
      for (int j = 0; j < 2; ++j)
        bfr[j] = *(const short8v*)&Ws[wn * 32 + j * 16 + l15][s * 32 + l16 * 8];
#pragma unroll
      for (int i = 0; i < 4; ++i)
#pragma unroll
        for (int j = 0; j < 2; ++j)
          acc[i][j] = __builtin_amdgcn_mfma_f32_16x16x32_bf16(a[i], bfr[j], acc[i][j], 0, 0, 0);
    }
  }
#pragma unroll
  for (int i = 0; i < 4; ++i)
#pragma unroll
    for (int j = 0; j < 2; ++j) {
      int col = col0 + wn * 32 + j * 16 + l15;
      int rbase = row0 + wm * 64 + i * 16 + l16 * 4;
      int ntok = ntok0 + wm * 64 + i * 16 + l16 * 4;
      if (flags == 2) {
        ushort4 pk = { f2bf(acc[i][j][0]), f2bf(acc[i][j][1]),
                       f2bf(acc[i][j][2]), f2bf(acc[i][j][3]) };
        *(ushort4*)&((ushort*)Cd)[((long)(btok * CDIM + col)) * 1024 + ntok] = pk;
      } else if (flags == 1) {
        ushort4 yv = *(const ushort4*)&ycr[((long)(btok * CDIM + col)) * 1024 + ntok];
        float bcol = bias[col];
        float* op = (float*)Cd;
        op[(long)(rbase + 0) * CDIM + col] = acc[i][j][0] + bcol + bf2f(yv.x);
        op[(long)(rbase + 1) * CDIM + col] = acc[i][j][1] + bcol + bf2f(yv.y);
        op[(long)(rbase + 2) * CDIM + col] = acc[i][j][2] + bcol + bf2f(yv.z);
        op[(long)(rbase + 3) * CDIM + col] = acc[i][j][3] + bcol + bf2f(yv.w);
      } else {
#pragma unroll
        for (int r = 0; r < 4; ++r)
          ((ushort*)Cd)[(long)(rbase + r) * CDIM + col] = f2bf(acc[i][j][r]);
      }
    }
}

// fused q/k/v projection GEMMs reading c-major conv outputs directly
// (trans_k eliminated).  z==2 (V) writes its output c-major.
__global__ __launch_bounds__(256) void gemm_qkv_k(
    const ushort* __restrict__ qc, const ushort* __restrict__ kc, const ushort* __restrict__ vc,
    const ushort* __restrict__ wqb, const ushort* __restrict__ wkb, const ushort* __restrict__ wvb,
    ushort* __restrict__ q1, ushort* __restrict__ k1, ushort* __restrict__ vtc)
{
  const int z = blockIdx.z;
  const ushort* A  = z == 0 ? qc  : z == 1 ? kc  : vc;
  const ushort* Wb = z == 0 ? wqb : z == 1 ? wkb : wvb;
  ushort*       C  = z == 0 ? q1  : z == 1 ? k1  : vtc;
  gemm_body<true>(A, Wb, nullptr, nullptr, C, z == 2 ? 2 : 0, blockIdx.x, blockIdx.y);
}

// final projection: out = A@wo^T + bo + x_fft (residual from yc)
__global__ __launch_bounds__(256) void gemm_out_k(
    const ushort* __restrict__ A, const ushort* __restrict__ Wb,
    const float* __restrict__ bias, const ushort* __restrict__ ycr,
    float* __restrict__ Cd)
{
  gemm_body<false>(A, Wb, bias, ycr, Cd, 1, blockIdx.x, blockIdx.y);
}

// ---------------------------------------------------------------------------
// Kernel 4: MFMA flash attention (r10 structure + T14-lite reg prefetch).
// Swapped QK^T, cvt_pk P pack, no-max softmax, ones-MFMA row sums, Q direct
// from global, single K/V LDS buffer with next-tile loads issued under
// compute.  V comes from vtc (c-major GEMM output).
// ---------------------------------------------------------------------------
__global__ __launch_bounds__(256) void attn_mfma_k(
    const ushort* __restrict__ q1, const ushort* __restrict__ k1,
    const ushort* __restrict__ vt, ushort* __restrict__ ao)
{
  const int bh = blockIdx.x, qt = blockIdx.y;
  const int b = bh >> 3, h = bh & 7;
  const int tid = threadIdx.x;
  const int w = tid >> 6, lane = tid & 63;
  const int l15 = lane & 15, l16 = lane >> 4;
  __shared__ ushort Ks[64][72], Vs[48][72], Ps[64][72];
  const float scale = 0.051031036307982884f;  // 384^-0.5
  const long base = (long)b * NPIX * CDIM + h * 48;
  const long vbase = (long)bh * 48 * NPIX;

  // per-thread staging descriptors (scalars -> no scratch).
  const int i0 = tid, i1 = tid + 256, i2 = tid + 512;
  const int r0 = i0 / 6, s0 = i0 - r0 * 6;
  const ushort* gp0 = k1 + base + (long)r0 * CDIM + s0 * 8;
  const long st0 = (long)64 * CDIM;
  ushort* lp0 = &Ks[r0][s0 * 8];
  const ushort* gp1; long st1; ushort* lp1;
  if (i1 < 384) {
    int r = i1 / 6, s = i1 - r * 6;
    gp1 = k1 + base + (long)r * CDIM + s * 8; st1 = (long)64 * CDIM; lp1 = &Ks[r][s * 8];
  } else {
    int j = i1 - 384, d = j >> 3, s = j & 7;
    gp1 = vt + vbase + (long)d * NPIX + s * 8; st1 = 64; lp1 = &Vs[d][s * 8];
  }
  const int j2 = i2 - 384, d2 = j2 >> 3, s2 = j2 & 7;
  const ushort* gp2 = vt + vbase + (long)d2 * NPIX + s2 * 8;
  const long st2 = 64;
  ushort* lp2 = &Vs[d2][s2 * 8];

  // zero K pad (cols 48..63), persists across iterations
  if (tid < 128) {
    uint4 z4 = {0u, 0u, 0u, 0u};
    int r = tid >> 1, s = tid & 1;
    *(uint4*)&Ks[r][48 + s * 8] = z4;
  }
  // Q fragments direct from global; d=48..63 lanes -> zero
  const long qrow = base + (long)(qt * 64 + w * 16 + l15) * CDIM;
  short8v qa0 = *(const short8v*)&q1[qrow + l16 * 8];
  short8v qa1;
  {
    short8v qz = {};
    short8v qv = *(const short8v*)&q1[qrow + ((l16 < 2) ? 32 + l16 * 8 : 0)];
    qa1 = (l16 < 2) ? qv : qz;
  }

  float lrun[4] = {0.f, 0.f, 0.f, 0.f};
  float4v accO[3];
#pragma unroll
  for (int fd = 0; fd < 3; ++fd) accO[fd] = (float4v){0.f, 0.f, 0.f, 0.f};
  short8v onesb;
#pragma unroll
  for (int j = 0; j < 8; ++j) onesb[j] = (short)0x3F80;  // bf16 1.0

  uint4 t0 = *(const uint4*)gp0;          // tile 0 loads
  uint4 t1 = *(const uint4*)gp1;
  uint4 t2 = *(const uint4*)gp2;

  for (int kt = 0; kt < 16; ++kt) {
    *(uint4*)lp0 = t0;
    *(uint4*)lp1 = t1;
    *(uint4*)lp2 = t2;
    __syncthreads();
    if (kt + 1 < 16) {                    // issue loads for t+1 under compute
      t0 = *(const uint4*)(gp0 + (long)(kt + 1) * st0);
      t1 = *(const uint4*)(gp1 + (long)(kt + 1) * st1);
      t2 = *(const uint4*)(gp2 + (long)(kt + 1) * st2);
    }
    // swapped QK^T: S^T[k][q]; lane q = l15, k = fc*16 + l16*4 + r
    float4v sacc[4];
#pragma unroll
    for (int fc = 0; fc < 4; ++fc) {
      short8v kb0 = *(const short8v*)&Ks[fc * 16 + l15][l16 * 8];
      short8v kb1 = *(const short8v*)&Ks[fc * 16 + l15][32 + l16 * 8];
      sacc[fc] = (float4v){0.f, 0.f, 0.f, 0.f};
      sacc[fc] = __builtin_amdgcn_mfma_f32_16x16x32_bf16(kb0, qa0, sacc[fc], 0, 0, 0);
      sacc[fc] = __builtin_amdgcn_mfma_f32_16x16x32_bf16(kb1, qa1, sacc[fc], 0, 0, 0);
    }
    // P = exp(S*scale); pack pairs of consecutive k -> dword stores
    unsigned* prow = (unsigned*)&Ps[w * 16 + l15][0];
#pragma unroll
    for (int fc = 0; fc < 4; ++fc) {
      float p0 = __expf(sacc[fc][0] * scale);
      float p1 = __expf(sacc[fc][1] * scale);
      float p2 = __expf(sacc[fc][2] * scale);
      float p3 = __expf(sacc[fc][3] * scale);
      __hip_bfloat162 d01 = __float22bfloat162_rn(make_float2(p0, p1));
      __hip_bfloat162 d23 = __float22bfloat162_rn(make_float2(p2, p3));
      prow[fc * 8 + l16 * 2 + 0] = *(unsigned*)&d01;
      prow[fc * 8 + l16 * 2 + 1] = *(unsigned*)&d23;
    }
    // Ps is wave-private: intra-wave DS drain, no block barrier
    asm volatile("s_waitcnt lgkmcnt(0)" ::: "memory");
    __builtin_amdgcn_sched_barrier(0);
    short8v pa0 = *(const short8v*)&Ps[w * 16 + l15][l16 * 8];
    short8v pa1 = *(const short8v*)&Ps[w * 16 + l15][32 + l16 * 8];
    // row sums via ones-MFMA (matrix pipe, reuses pa fragments)
    float4v srow = (float4v){0.f, 0.f, 0.f, 0.f};
    srow = __builtin_amdgcn_mfma_f32_16x16x32_bf16(pa0, onesb, srow, 0, 0, 0);
    srow = __builtin_amdgcn_mfma_f32_16x16x32_bf16(pa1, onesb, srow, 0, 0, 0);
#pragma unroll
    for (int r = 0; r < 4; ++r) lrun[r] += srow[r];
    // PV: O(16x48) += P(16x64) . V(64x48)
#pragma unroll
    for (int fd = 0; fd < 3; ++fd) {
      short8v vb0 = *(const short8v*)&Vs[fd * 16 + l15][l16 * 8];
      short8v vb1 = *(const short8v*)&Vs[fd * 16 + l15][32 + l16 * 8];
      accO[fd] = __builtin_amdgcn_mfma_f32_16x16x32_bf16(pa0, vb0, accO[fd], 0, 0, 0);
      accO[fd] = __builtin_amdgcn_mfma_f32_16x16x32_bf16(pa1, vb1, accO[fd], 0, 0, 0);
    }
    __syncthreads();                      // compute done; LDS free for t+1
  }
  float inv[4];
#pragma unroll
  for (int r = 0; r < 4; ++r) inv[r] = 1.f / lrun[r];
#pragma unroll
  for (int fd = 0; fd < 3; ++fd)
#pragma unroll
    for (int r = 0; r < 4; ++r) {
      int qrow2 = qt * 64 + w * 16 + l16 * 4 + r;
      ao[base + (long)qrow2 * CDIM + fd * 16 + l15] = f2bf(accO[fd][r] * inv[r]);
    }
}

// ---------------------------------------------------------------------------
extern "C" void kernel_launch(void* const* d_in, const int* in_sizes, int n_in,
                              void* d_out, int out_size, void* d_ws, size_t ws_size,
                              hipStream_t stream) {
  const float* x   = (const float*)d_in[0];
  const float* cw  = (const float*)d_in[1];
  const float* dwq = (const float*)d_in[2];
  const float* dwk = (const float*)d_in[3];
  const float* dwv = (const float*)d_in[4];
  const float* gq  = (const float*)d_in[5];
  const float* bq  = (const float*)d_in[6];
  const float* mq  = (const float*)d_in[7];
  const float* vq  = (const float*)d_in[8];
  const float* gk  = (const float*)d_in[9];
  const float* bk  = (const float*)d_in[10];
  const float* mk  = (const float*)d_in[11];
  const float* vk  = (const float*)d_in[12];
  const float* gv  = (const float*)d_in[13];
  const float* bv  = (const float*)d_in[14];
  const float* mv  = (const float*)d_in[15];
  const float* vv  = (const float*)d_in[16];
  const float* wq  = (const float*)d_in[17];
  const float* wk  = (const float*)d_in[18];
  const float* wv  = (const float*)d_in[19];
  const float* wo  = (const float*)d_in[20];
  const float* bo  = (const float*)d_in[21];
  float* out = (float*)d_out;

  char* wsb = (char*)d_ws;
  const size_t H = (size_t)NB * NPIX * CDIM * 2;        // 6,291,456 B
  // slot plan (each H):
  // S0: xc -> vtc | S1: yc | S2: qc -> ao | S3: kc | S4: vc
  // S5: q1 | S6: k1 | S7: weights + tbl
  ushort* xcp = (ushort*)(wsb + 0 * H);
  ushort* vtc = (ushort*)(wsb + 0 * H);
  ushort* yc  = (ushort*)(wsb + 1 * H);
  ushort* qc  = (ushort*)(wsb + 2 * H);
  ushort* ao  = (ushort*)(wsb + 2 * H);
  ushort* kc  = (ushort*)(wsb + 3 * H);
  ushort* vc  = (ushort*)(wsb + 4 * H);
  ushort* q1  = (ushort*)(wsb + 5 * H);
  ushort* k1  = (ushort*)(wsb + 6 * H);
  ushort* wqb = (ushort*)(wsb + 7 * H);
  ushort* wkb = wqb + CDIM * CDIM;
  ushort* wvb = wkb + CDIM * CDIM;
  ushort* wob = wvb + CDIM * CDIM;
  ushort* tbl = wob + CDIM * CDIM;                      // 5*1024 ushorts

  prep_k<<<dim3(932), 256, 0, stream>>>(tbl, wq, wk, wv, wo,
      wqb, wkb, wvb, wob, x, xcp);
  fft_conv_k<<<dim3(NB * CDIM), 256, 0, stream>>>(xcp, cw, tbl, dwq, dwk, dwv,
      gq, bq, mq, vq, gk, bk, mk, vk, gv, bv, mv, vv, yc, qc, kc, vc);
  // gemm reads qc/kc/vc (c-major) directly; z=2 writes vtc (S0, xc dead) c-major
  gemm_qkv_k<<<dim3(64, 6, 3), 256, 0, stream>>>(qc, kc, vc, wqb, wkb, wvb, q1, k1, vtc);
  attn_mfma_k<<<dim3(64, 16), 256, 0, stream>>>(q1, k1, vtc, ao);
  gemm_out_k<<<dim3(64, 6), 256, 0, stream>>>(ao, wob, bo, yc, out);
}